// Round 13
// baseline (274.268 us; speedup 1.0000x reference)
//
#include <hip/hip_runtime.h>
#include <cstdint>
#include <cmath>

typedef unsigned short u16;
typedef unsigned int u32;
typedef unsigned long long u64;
typedef __bf16 bf16x8 __attribute__((ext_vector_type(8)));
typedef float f32x4 __attribute__((ext_vector_type(4)));
typedef float f32x16 __attribute__((ext_vector_type(16)));
typedef int v2i __attribute__((ext_vector_type(2)));

#define AS1 __attribute__((address_space(1)))
#define AS3 __attribute__((address_space(3)))

static constexpr int DM = 1024, DFF = 4096, SS = 2048, HH = 16, HD = 64, TT = 4096;
static constexpr size_t MiB = (size_t)1 << 20;
static constexpr size_t OFF_WQKVT = 0;          // 6 MiB
static constexpr size_t OFF_WOT = 6 * MiB;      // 2 MiB
static constexpr size_t OFF_W1T = 8 * MiB;      // 8 MiB
static constexpr size_t OFF_W2T = 16 * MiB;     // 8 MiB
static constexpr size_t OFF_XB = 24 * MiB;      // 8 MiB xb -> Ob -> ffn1(lo)
static constexpr size_t OFF_QB = 32 * MiB;      // 8 MiB -> attn0(lo)
static constexpr size_t OFF_KB = 40 * MiB;      // 8 MiB -> attn0(hi)
static constexpr size_t OFF_VT = 48 * MiB;      // 8 MiB blocked V^T -> hb
static constexpr size_t OFF_OPART = 56 * MiB;   // 32 MiB u16[4][65536][64] -> attn1 / f1
static constexpr size_t OFF_ML = 88 * MiB;      // 1 MiB float[4][65536]
static constexpr size_t OFF_BQKV = 90 * MiB;    // 12 KiB
static constexpr size_t OFF_ATTN0 = 32 * MiB;   // 16 MiB f32 (over QB+KB)
static constexpr size_t OFF_ATTN1 = 56 * MiB;   // 16 MiB f32 (over Opart, post-merge)
static constexpr size_t OFF_HB = 48 * MiB;      // 8 MiB bf16 h (over VT)
static constexpr size_t OFF_F1 = 56 * MiB;      // 32 MiB bf16 gelu out (post-LN1)
static constexpr size_t OFF_FFN0 = 0;           // 16 MiB f32 (over weights)
static constexpr size_t OFF_FFN1 = 24 * MiB;    // 16 MiB f32 (over Ob+attn0lo)

__device__ __forceinline__ u16 f2bf(float f) {
  union { float f; unsigned u; } c; c.f = f;
  unsigned r = c.u + 0x7fffu + ((c.u >> 16) & 1u);
  return (u16)(r >> 16);
}
__device__ __forceinline__ float bf2f(u16 h) {
  union { unsigned u; float f; } c; c.u = ((u32)h) << 16;
  return c.f;
}

__device__ __forceinline__ void gload_lds16(const void* g, void* l) {
  __builtin_amdgcn_global_load_lds((AS1 void*)g, (AS3 void*)l, 16, 0, 0);
}

__device__ __forceinline__ float exp2_(float x) {
#if __has_builtin(__builtin_amdgcn_exp2f)
  return __builtin_amdgcn_exp2f(x);
#else
  return exp2f(x);
#endif
}

__device__ __forceinline__ u32 cvt_pk_bf16(float lo, float hi) {
  u32 r;
  asm("v_cvt_pk_bf16_f32 %0, %1, %2" : "=v"(r) : "v"(lo), "v"(hi));
  return r;
}

__device__ __forceinline__ void lane32_swap(u32& a, u32& b) {
#if __has_builtin(__builtin_amdgcn_permlane32_swap)
  v2i r = __builtin_amdgcn_permlane32_swap((int)a, (int)b, false, false);
  a = (u32)r.x;
  b = (u32)r.y;
#else
  u32 ta = (u32)__shfl_xor((int)a, 32);
  u32 tb = (u32)__shfl_xor((int)b, 32);
  bool hi = (threadIdx.x & 32) != 0;
  u32 na = hi ? tb : a;
  u32 nb = hi ? b : ta;
  a = na;
  b = nb;
#endif
}

__device__ __forceinline__ float cross32_reduce_sum(float x) {
  u32 a = __float_as_uint(x), b = a;
  lane32_swap(a, b);
  return __uint_as_float(a) + __uint_as_float(b);
}

__device__ __forceinline__ int xcd_swizzle(int bid, int nwg) {
  int q8 = nwg >> 3;
  return (bid & 7) * q8 + (bid >> 3);
}

// ---------------- cast fp32 -> bf16 ----------------
__global__ __launch_bounds__(256) void k_cast(const float* __restrict__ in,
                                              u16* __restrict__ out, int n4) {
  int i = blockIdx.x * 256 + threadIdx.x;
  if (i < n4) {
    float4 v = ((const float4*)in)[i];
    u64 pk = (u64)f2bf(v.x) | ((u64)f2bf(v.y) << 16) |
             ((u64)f2bf(v.z) << 32) | ((u64)f2bf(v.w) << 48);
    ((u64*)out)[i] = pk;
  }
}

// ------------- transpose+cast: in fp32 [R][C] -> out bf16 [C][R] -------------
__global__ __launch_bounds__(256) void k_transpose_cast(const float* __restrict__ in,
                                                        u16* __restrict__ out,
                                                        int R, int C) {
  __shared__ u16 tile[32][33];
  const int cb = blockIdx.x * 32, rb = blockIdx.y * 32;
  const int tx = threadIdx.x & 31;
  const int ty = threadIdx.x >> 5;
#pragma unroll
  for (int i = 0; i < 4; i++) {
    int r = ty + i * 8;
    tile[r][tx] = f2bf(in[(size_t)(rb + r) * C + cb + tx]);
  }
  __syncthreads();
#pragma unroll
  for (int i = 0; i < 4; i++) {
    int r2 = ty + i * 8;
    out[(size_t)(cb + r2) * R + rb + tx] = tile[tx][r2];
  }
}

// ---------------- concat 3 bias vectors ----------------
__global__ __launch_bounds__(256) void k_concat3(const float* __restrict__ a,
                                                 const float* __restrict__ b,
                                                 const float* __restrict__ c,
                                                 float* __restrict__ out) {
  int i = blockIdx.x * 256 + threadIdx.x;
  if (i < 3072) out[i] = i < 1024 ? a[i] : (i < 2048 ? b[i - 1024] : c[i - 2048]);
}

enum { EPI_F32 = 0, EPI_GELU = 1, EPI_QKV3 = 2 };

// ======== 128x128 4-wave BK=64 GEMM, 64 KiB LDS dbuf => 2 independent blocks/CU ========
// Per K-tile: issue next stage (8 gload16/thread-group) first; 16 ds_read_b128 + 32 MFMA
// cover its latency; single __syncthreads (drains vmcnt+lgkm) per tile. The m114
// mechanism (2 resident blocks) hides the drain. XOR-swizzled 128B rows (conflict-free).
template <int EPI>
__global__ __launch_bounds__(256) void k_g128(const u16* __restrict__ A,
                                              const u16* __restrict__ Bt,
                                              const float* __restrict__ bias,
                                              void* __restrict__ Cout,
                                              int N, int Ksub, int stride,
                                              size_t zoff, int nx, int ny) {
  __shared__ __align__(16) u16 Al[2][8192];  // [buf][128 rows x 64 k]
  __shared__ __align__(16) u16 Bl[2][8192];
  const int tid = threadIdx.x;
  const int wid = tid >> 6, lane = tid & 63;
  const int lrow = lane & 15, lgrp = lane >> 4;
  const int wr = wid >> 1, wc = wid & 1;  // wave grid 2M x 2N, 64x64 each
  const int swz = xcd_swizzle(blockIdx.x, gridDim.x);
  const int bx = swz % nx;
  const int by = (swz / nx) % ny;
  const int bz = swz / (nx * ny);
  const int mrow = by * 128, ncol = bx * 128;

  const int srow = tid >> 3;  // 0..31 (row within 32-row chunk)
  const int sgd = tid & 7;
  const int gsw = (sgd ^ (srow & 7)) << 3;  // pre-swizzled source granule (elems)
  const u16* aS0 = A + (size_t)(mrow + srow) * stride + (size_t)bz * Ksub + gsw;
  const u16* bS0 = Bt + (size_t)(ncol + srow) * stride + (size_t)bz * Ksub + gsw;
  const int T = Ksub >> 6;

  auto stage = [&](int t, int b) {
    char* ad = (char*)&Al[b][0] + wid * 1024;
    char* bd = (char*)&Bl[b][0] + wid * 1024;
    const u16* as = aS0 + t * 64;
    const u16* bs = bS0 + t * 64;
#pragma unroll
    for (int c = 0; c < 4; ++c) {
      gload_lds16(as + (size_t)c * 32 * stride, ad + c * 4096);
      gload_lds16(bs + (size_t)c * 32 * stride, bd + c * 4096);
    }
  };

  f32x4 acc[4][4];
#pragma unroll
  for (int m = 0; m < 4; ++m)
#pragma unroll
    for (int n = 0; n < 4; ++n) acc[m][n] = (f32x4){0.f, 0.f, 0.f, 0.f};

  stage(0, 0);
  __syncthreads();  // drains vmcnt(0): tile 0 landed

  const int arow = wr * 64 + lrow;  // + m*16
  const int brow = wc * 64 + lrow;  // + n*16
  const int aswz = lrow & 7;

  for (int t = 0; t < T; ++t) {
    if (t + 1 < T) stage(t + 1, (t + 1) & 1);
    const char* Ab = (const char*)&Al[t & 1][0];
    const char* Bb = (const char*)&Bl[t & 1][0];
    bf16x8 af[4][2], bfr[4][2];
#pragma unroll
    for (int m = 0; m < 4; ++m)
#pragma unroll
      for (int ks = 0; ks < 2; ++ks)
        af[m][ks] = *(const bf16x8*)(Ab + (arow + m * 16) * 128 +
                                     (((ks * 4 + lgrp) ^ aswz) << 4));
#pragma unroll
    for (int n = 0; n < 4; ++n)
#pragma unroll
      for (int ks = 0; ks < 2; ++ks)
        bfr[n][ks] = *(const bf16x8*)(Bb + (brow + n * 16) * 128 +
                                      (((ks * 4 + lgrp) ^ aswz) << 4));
    __builtin_amdgcn_s_setprio(1);
#pragma unroll
    for (int m = 0; m < 4; ++m)
#pragma unroll
      for (int n = 0; n < 4; ++n)
#pragma unroll
        for (int ks = 0; ks < 2; ++ks)
          acc[m][n] = __builtin_amdgcn_mfma_f32_16x16x32_bf16(af[m][ks], bfr[n][ks],
                                                              acc[m][n], 0, 0, 0);
    __builtin_amdgcn_s_setprio(0);
    __syncthreads();  // drains vmcnt (next tile landed) + lgkm
  }

#pragma unroll
  for (int m = 0; m < 4; ++m) {
#pragma unroll
    for (int n = 0; n < 4; ++n) {
      const int row0 = mrow + wr * 64 + m * 16 + lgrp * 4;
      const int col = ncol + wc * 64 + n * 16 + lrow;
      f32x4 v = acc[m][n];
      if constexpr (EPI == EPI_GELU) {
        const float bv = bias[col];
        u16* C = (u16*)Cout;
#pragma unroll
        for (int r = 0; r < 4; r++) {
          float xg = v[r] + bv;
          float gl = 0.5f * xg * (1.0f + erff(xg * 0.70710678118654752f));
          C[(size_t)(row0 + r) * N + col] = f2bf(gl);
        }
      } else if constexpr (EPI == EPI_QKV3) {
        const float bv = bias[col];
        char* wsb = (char*)Cout;
        const int seg = col >> 10, cc = col & 1023;
        const int h = cc >> 6, d = cc & 63;
        if (seg < 2) {
          u16* dst = (u16*)(wsb + (seg == 0 ? OFF_QB : OFF_KB));
#pragma unroll
          for (int r = 0; r < 4; r++) {
            const int row = row0 + r;
            const int b = row >> 11, s = row & 2047;
            dst[((size_t)(b * HH + h) * SS + s) * HD + d] = f2bf(v[r] + bv);
          }
        } else {
          u16* Vt = (u16*)(wsb + OFF_VT);
          const int b = row0 >> 11, s = row0 & 2047;
          u64 pk = (u64)f2bf(v[0] + bv) | ((u64)f2bf(v[1] + bv) << 16) |
                   ((u64)f2bf(v[2] + bv) << 32) | ((u64)f2bf(v[3] + bv) << 48);
          size_t addr = ((size_t)(b * HH + h) * (SS / 64) + (s >> 6)) * 4096 +
                        (size_t)d * 64 + (s & 63);
          *(u64*)&Vt[addr] = pk;
        }
      } else {
        const float bv = (bz == 0) ? bias[col] : 0.0f;
        float* C = (float*)Cout + (size_t)bz * zoff;
#pragma unroll
        for (int r = 0; r < 4; r++) C[(size_t)(row0 + r) * N + col] = v[r] + bv;
      }
    }
  }
}

// ---------------- flash attention, KV-split=4, KVBLK=64, fixed-C softmax ----------------
__global__ __launch_bounds__(256) void k_attn_split(const u16* __restrict__ Q,
                                                    const u16* __restrict__ K,
                                                    const u16* __restrict__ Vt,
                                                    u16* __restrict__ Opart,
                                                    float* __restrict__ lpart) {
  __shared__ __align__(16) u16 Kl[2][4096];
  __shared__ __align__(16) u16 Vl[2][4096];
  const int tid = threadIdx.x, wid = tid >> 6, lane = tid & 63;
  const int ql = lane & 31, hi = lane >> 5;
  const int bx = blockIdx.x;
  const int split = bx >> 9, bh = (bx >> 4) & 31, qblk = bx & 15;
  const int qbase = qblk * 128 + wid * 32;
  const int kvS = split * 512;
  const u16* Qh = Q + (size_t)bh * SS * HD;
  const u16* Kh = K + (size_t)bh * SS * HD;
  const u16* Vh = Vt + (size_t)bh * SS * HD;

  const int lrow3 = lane >> 3;
  const int lin = lrow3 * 128 + ((((lane & 7) << 4)) ^ (lrow3 << 4));
  const int kswz = (ql & 7) << 4;

  auto stage = [&](int kv0, int bufi) {
    const char* Ks = (const char*)Kh + (size_t)kv0 * 128 + wid * 2048 + lin;
    const char* Vs = (const char*)Vh + ((size_t)(kv0 >> 6)) * 8192 + wid * 2048 + lin;
    char* kd = (char*)&Kl[bufi][0] + wid * 2048;
    char* vd = (char*)&Vl[bufi][0] + wid * 2048;
    gload_lds16(Ks, kd);
    gload_lds16(Ks + 1024, kd + 1024);
    gload_lds16(Vs, vd);
    gload_lds16(Vs + 1024, vd + 1024);
  };

  bf16x8 qf[4];
#pragma unroll
  for (int j = 0; j < 4; j++)
    qf[j] = *(const bf16x8*)&Qh[(size_t)(qbase + ql) * HD + j * 16 + hi * 8];

  f32x16 oacc0, oacc1;
#pragma unroll
  for (int r = 0; r < 16; r++) { oacc0[r] = 0.f; oacc1[r] = 0.f; }
  float lsum = 0.f;
  const float cs = 0.125f * 1.44269504f;
  const float CSHIFT = 24.0f;

  auto tileC = [&](int bufi, int tt) {
    const char* Kb = (const char*)&Kl[bufi][0];
    const char* Vb = (const char*)&Vl[bufi][0];
    bf16x8 kf[4];
#pragma unroll
    for (int j = 0; j < 4; j++)
      kf[j] = *(const bf16x8*)(Kb + (tt * 32 + ql) * 128 + ((j * 32 + hi * 16) ^ kswz));

    f32x16 s;
#pragma unroll
    for (int r = 0; r < 16; r++) s[r] = 0.f;
#pragma unroll
    for (int j = 0; j < 4; j++)
      s = __builtin_amdgcn_mfma_f32_32x32x16_bf16(kf[j], qf[j], s, 0, 0, 0);

    float p[16];
#pragma unroll
    for (int r = 0; r < 16; r++) p[r] = exp2_(fmaf(s[r], cs, -CSHIFT));
    float t0 = (p[0] + p[1]) + (p[2] + p[3]);
    float t1 = (p[4] + p[5]) + (p[6] + p[7]);
    float t2 = (p[8] + p[9]) + (p[10] + p[11]);
    float t3 = (p[12] + p[13]) + (p[14] + p[15]);
    lsum += cross32_reduce_sum((t0 + t1) + (t2 + t3));

    u32 w01 = cvt_pk_bf16(p[0], p[1]), w23 = cvt_pk_bf16(p[2], p[3]);
    u32 w45 = cvt_pk_bf16(p[4], p[5]), w67 = cvt_pk_bf16(p[6], p[7]);
    u32 w89 = cvt_pk_bf16(p[8], p[9]), wab = cvt_pk_bf16(p[10], p[11]);
    u32 wcd = cvt_pk_bf16(p[12], p[13]), wef = cvt_pk_bf16(p[14], p[15]);
    lane32_swap(w01, w45);
    lane32_swap(w23, w67);
    lane32_swap(w89, wcd);
    lane32_swap(wab, wef);
    union { u32 w[4]; bf16x8 v; } f0, f1;
    f0.w[0] = w01; f0.w[1] = w23; f0.w[2] = w45; f0.w[3] = w67;
    f1.w[0] = w89; f1.w[1] = wab; f1.w[2] = wcd; f1.w[3] = wef;

    bf16x8 vf[4];
#pragma unroll
    for (int u = 0; u < 4; u++)
      vf[u] = *(const bf16x8*)(Vb + ((u >> 1) * 32 + ql) * 128 +
                               ((tt * 64 + (u & 1) * 32 + hi * 16) ^ kswz));

    oacc0 = __builtin_amdgcn_mfma_f32_32x32x16_bf16(vf[0], f0.v, oacc0, 0, 0, 0);
    oacc0 = __builtin_amdgcn_mfma_f32_32x32x16_bf16(vf[1], f1.v, oacc0, 0, 0, 0);
    oacc1 = __builtin_amdgcn_mfma_f32_32x32x16_bf16(vf[2], f0.v, oacc1, 0, 0, 0);
    oacc1 = __builtin_amdgcn_mfma_f32_32x32x16_bf16(vf[3], f1.v, oacc1, 0, 0, 0);
  };

  stage(kvS, 0);
  __syncthreads();
  int cur = 0;
  for (int it = 0; it < 8; ++it) {
    if (it + 1 < 8) stage(kvS + (it + 1) * 64, cur ^ 1);
    tileC(cur, 0);
    tileC(cur, 1);
    __syncthreads();
    cur ^= 1;
  }

  const int rowidx = bh * SS + qbase + ql;
  u16* Orow = Opart + ((size_t)split * 32 * SS + rowidx) * HD;
  auto storeAcc = [&](const f32x16& a, int dbase) {
#pragma unroll
    for (int t = 0; t < 4; t++) {
      u64 pk = (u64)f2bf(a[4 * t]) | ((u64)f2bf(a[4 * t + 1]) << 16) |
               ((u64)f2bf(a[4 * t + 2]) << 32) | ((u64)f2bf(a[4 * t + 3]) << 48);
      *(u64*)&Orow[dbase + 4 * hi + 8 * t] = pk;
    }
  };
  storeAcc(oacc0, 0);
  storeAcc(oacc1, 32);
  if (hi == 0) lpart[(size_t)split * 32 * SS + rowidx] = lsum;
}

// ---------------- merge the 4 KV-split partials (plain sums) -> bf16 O ----------------
__global__ __launch_bounds__(256) void k_attn_merge(const u16* __restrict__ Opart,
                                                    const float* __restrict__ lpart,
                                                    u16* __restrict__ O) {
  const int g = blockIdx.x * 256 + threadIdx.x;
  const int row = g >> 4, dseg = g & 15;
  float denom = 0.f;
#pragma unroll
  for (int s = 0; s < 4; s++) denom += lpart[(size_t)s * 32 * SS + row];
  const float inv = 1.0f / denom;
  float acc[4] = {0.f, 0.f, 0.f, 0.f};
#pragma unroll
  for (int s = 0; s < 4; s++) {
    u64 pk = *(const u64*)&Opart[(((size_t)s * 32 * SS + row) * HD) + dseg * 4];
#pragma unroll
    for (int k = 0; k < 4; k++) acc[k] += bf2f((u16)(pk >> (16 * k)));
  }
  const int bh = row >> 11, s2 = row & 2047;
  const int bb = bh >> 4, h = bh & 15;
  u64 pk = (u64)f2bf(acc[0] * inv) | ((u64)f2bf(acc[1] * inv) << 16) |
           ((u64)f2bf(acc[2] * inv) << 32) | ((u64)f2bf(acc[3] * inv) << 48);
  *(u64*)&O[((size_t)(bb * SS + s2) * DM) + h * HD + dseg * 4] = pk;
}

// ---------------- fused residual(2-way) + layernorm ----------------
template <bool XBF, bool WB>
__global__ __launch_bounds__(256) void k_res_ln(const void* __restrict__ Xv,
                                                const float* __restrict__ Y0,
                                                const float* __restrict__ Y1,
                                                const float* __restrict__ gw,
                                                const float* __restrict__ bw,
                                                float* __restrict__ outf,
                                                u16* __restrict__ outb) {
  const int row = blockIdx.x, t = threadIdx.x;
  float x0, x1, x2, x3;
  if constexpr (XBF) {
    u64 pk = ((const u64*)Xv)[(size_t)row * 256 + t];
    x0 = bf2f((u16)pk);
    x1 = bf2f((u16)(pk >> 16));
    x2 = bf2f((u16)(pk >> 32));
    x3 = bf2f((u16)(pk >> 48));
  } else {
    float4 xv = ((const float4*)Xv)[(size_t)row * 256 + t];
    x0 = xv.x; x1 = xv.y; x2 = xv.z; x3 = xv.w;
  }
  const float4 y0 = ((const float4*)(Y0 + (size_t)row * DM))[t];
  const float4 y1 = ((const float4*)(Y1 + (size_t)row * DM))[t];
  float v0 = x0 + y0.x + y1.x, v1 = x1 + y0.y + y1.y;
  float v2 = x2 + y0.z + y1.z, v3 = x3 + y0.w + y1.w;
  float s = v0 + v1 + v2 + v3;
  float s2 = v0 * v0 + v1 * v1 + v2 * v2 + v3 * v3;
#pragma unroll
  for (int off = 32; off >= 1; off >>= 1) {
    s += __shfl_down(s, off);
    s2 += __shfl_down(s2, off);
  }
  __shared__ float ps[4], ps2[4];
  const int wid = t >> 6, lane = t & 63;
  if (lane == 0) { ps[wid] = s; ps2[wid] = s2; }
  __syncthreads();
  const float ts = ps[0] + ps[1] + ps[2] + ps[3];
  const float ts2 = ps2[0] + ps2[1] + ps2[2] + ps2[3];
  const float mu = ts * (1.f / 1024.f);
  const float rs = rsqrtf(ts2 * (1.f / 1024.f) - mu * mu + 1e-5f);
  const float4 g4 = ((const float4*)gw)[t];
  const float4 b4 = ((const float4*)bw)[t];
  float o0 = (v0 - mu) * rs * g4.x + b4.x;
  float o1 = (v1 - mu) * rs * g4.y + b4.y;
  float o2 = (v2 - mu) * rs * g4.z + b4.z;
  float o3 = (v3 - mu) * rs * g4.w + b4.w;
  if constexpr (WB) {
    u64 pk = (u64)f2bf(o0) | ((u64)f2bf(o1) << 16) | ((u64)f2bf(o2) << 32) |
             ((u64)f2bf(o3) << 48);
    ((u64*)(outb + (size_t)row * DM))[t] = pk;
  } else {
    ((float4*)(outf + (size_t)row * DM))[t] = make_float4(o0, o1, o2, o3);
  }
}

extern "C" void kernel_launch(void* const* d_in, const int* in_sizes, int n_in,
                              void* d_out, int out_size, void* d_ws, size_t ws_size,
                              hipStream_t stream) {
  const float* x = (const float*)d_in[0];
  const float* Wq = (const float*)d_in[1];
  const float* bq = (const float*)d_in[2];
  const float* Wk = (const float*)d_in[3];
  const float* bk = (const float*)d_in[4];
  const float* Wv = (const float*)d_in[5];
  const float* bv = (const float*)d_in[6];
  const float* Wo = (const float*)d_in[7];
  const float* bo = (const float*)d_in[8];
  const float* g1 = (const float*)d_in[9];
  const float* b1 = (const float*)d_in[10];
  const float* g2 = (const float*)d_in[11];
  const float* b2 = (const float*)d_in[12];
  const float* W1 = (const float*)d_in[13];
  const float* bf1 = (const float*)d_in[14];
  const float* W2 = (const float*)d_in[15];
  const float* bf2 = (const float*)d_in[16];
  float* out = (float*)d_out;

  if (ws_size < 92 * MiB) return;
  char* ws = (char*)d_ws;
  u16* WqkvT = (u16*)(ws + OFF_WQKVT);
  u16* WoT = (u16*)(ws + OFF_WOT);
  u16* W1T = (u16*)(ws + OFF_W1T);
  u16* W2T = (u16*)(ws + OFF_W2T);
  u16* xb = (u16*)(ws + OFF_XB);
  u16* Qb = (u16*)(ws + OFF_QB);
  u16* Kb = (u16*)(ws + OFF_KB);
  u16* Vt = (u16*)(ws + OFF_VT);
  u16* Ob = (u16*)(ws + OFF_XB);
  u16* Opart = (u16*)(ws + OFF_OPART);
  float* lpart = (float*)(ws + OFF_ML);
  float* bqkv = (float*)(ws + OFF_BQKV);
  float* attn0 = (float*)(ws + OFF_ATTN0);
  float* attn1 = (float*)(ws + OFF_ATTN1);
  u16* hb = (u16*)(ws + OFF_HB);
  u16* f1 = (u16*)(ws + OFF_F1);
  float* ffn0 = (float*)(ws + OFF_FFN0);
  float* ffn1 = (float*)(ws + OFF_FFN1);

  k_cast<<<4096, 256, 0, stream>>>(x, xb, TT * DM / 4);
  k_transpose_cast<<<dim3(32, 32), 256, 0, stream>>>(Wq, WqkvT, DM, DM);
  k_transpose_cast<<<dim3(32, 32), 256, 0, stream>>>(Wk, WqkvT + 1024 * 1024, DM, DM);
  k_transpose_cast<<<dim3(32, 32), 256, 0, stream>>>(Wv, WqkvT + 2048 * 1024, DM, DM);
  k_transpose_cast<<<dim3(32, 32), 256, 0, stream>>>(Wo, WoT, DM, DM);
  k_transpose_cast<<<dim3(128, 32), 256, 0, stream>>>(W1, W1T, DM, DFF);
  k_transpose_cast<<<dim3(32, 128), 256, 0, stream>>>(W2, W2T, DFF, DM);
  k_concat3<<<12, 256, 0, stream>>>(bq, bk, bv, bqkv);

  // fused QKV projection: 128^2 tiles, grid 24x32 = 768 (3 blocks/CU queued, 2 resident)
  k_g128<EPI_QKV3><<<768, 256, 0, stream>>>(xb, WqkvT, bqkv, ws, 3072, DM, DM, 0,
                                            24, 32);

  // flash attention: split=4, grid 2048, KVBLK=64
  k_attn_split<<<2048, 256, 0, stream>>>(Qb, Kb, Vt, Opart, lpart);
  k_attn_merge<<<4096, 256, 0, stream>>>(Opart, lpart, Ob);

  // Wo projection: 128^2 tiles, split-K=2 -> grid 8*32*2 = 512
  k_g128<EPI_F32><<<512, 256, 0, stream>>>(Ob, WoT, bo, attn0, DM, DM / 2, DM,
                                           (OFF_ATTN1 - OFF_ATTN0) / 4, 8, 32);
  k_res_ln<false, true><<<4096, 256, 0, stream>>>(x, attn0, attn1, g1, b1, nullptr, hb);

  // FFN1: 128^2 tiles, grid 32x32 = 1024
  k_g128<EPI_GELU><<<1024, 256, 0, stream>>>(hb, W1T, bf1, f1, DFF, DM, DM, 0,
                                             32, 32);

  // FFN2: 128^2 tiles, split-K=2 -> grid 8*32*2 = 512
  k_g128<EPI_F32><<<512, 256, 0, stream>>>(f1, W2T, bf2, ffn0, DM, DFF / 2, DFF,
                                           (OFF_FFN1 - OFF_FFN0) / 4, 8, 32);
  k_res_ln<true, false><<<4096, 256, 0, stream>>>(hb, ffn0, ffn1, g2, b2, out, nullptr);
}

// Round 15
// 252.194 us; speedup vs baseline: 1.0875x; 1.0875x over previous
//
#include <hip/hip_runtime.h>
#include <cstdint>
#include <cmath>

typedef unsigned short u16;
typedef unsigned int u32;
typedef unsigned long long u64;
typedef __bf16 bf16x8 __attribute__((ext_vector_type(8)));
typedef float f32x4 __attribute__((ext_vector_type(4)));
typedef float f32x16 __attribute__((ext_vector_type(16)));
typedef int v2i __attribute__((ext_vector_type(2)));

#define AS1 __attribute__((address_space(1)))
#define AS3 __attribute__((address_space(3)))

static constexpr int DM = 1024, DFF = 4096, SS = 2048, HH = 16, HD = 64, TT = 4096;
static constexpr size_t MiB = (size_t)1 << 20;
// workspace map (bytes) — live-range audited:
// 0-6: WqkvT (dead after QKV) | 6-8: WoT (dead after Wo) | 8-16: W1T (dead after FFN1)
// 16-24: W2T (dead after FFN2) | 24-32: xb->Ob (dead after Wo) -> ffn0 partial
// 32-40: QB (dead after attn) -> attn0 partial (dead after LN1) -> ffn1 partial
// 40-48: KB (dead after attn) -> attn1 partial (dead after LN1)
// 48-56: VT (dead after attn) -> hb (live to LN2)
// 56-88: Opart (dead after merge) -> f1 (live to FFN2)
// 88-89: lpart | 90: bqkv
static constexpr size_t OFF_WQKVT = 0;
static constexpr size_t OFF_WOT = 6 * MiB;
static constexpr size_t OFF_W1T = 8 * MiB;
static constexpr size_t OFF_W2T = 16 * MiB;
static constexpr size_t OFF_XB = 24 * MiB;
static constexpr size_t OFF_QB = 32 * MiB;
static constexpr size_t OFF_KB = 40 * MiB;
static constexpr size_t OFF_VT = 48 * MiB;
static constexpr size_t OFF_OPART = 56 * MiB;
static constexpr size_t OFF_ML = 88 * MiB;
static constexpr size_t OFF_BQKV = 90 * MiB;
static constexpr size_t OFF_ATTN0 = 32 * MiB;  // bf16 partial, 8 MiB
static constexpr size_t OFF_ATTN1 = 40 * MiB;  // bf16 partial, 8 MiB
static constexpr size_t OFF_HB = 48 * MiB;     // bf16 h, 8 MiB
static constexpr size_t OFF_F1 = 56 * MiB;     // bf16 gelu out, 32 MiB
static constexpr size_t OFF_FFN0 = 24 * MiB;   // bf16 partial, 8 MiB
static constexpr size_t OFF_FFN1 = 32 * MiB;   // bf16 partial, 8 MiB

__device__ __forceinline__ u16 f2bf(float f) {
  union { float f; unsigned u; } c; c.f = f;
  unsigned r = c.u + 0x7fffu + ((c.u >> 16) & 1u);
  return (u16)(r >> 16);
}
__device__ __forceinline__ float bf2f(u16 h) {
  union { unsigned u; float f; } c; c.u = ((u32)h) << 16;
  return c.f;
}

__device__ __forceinline__ void gload_lds16(const void* g, void* l) {
  __builtin_amdgcn_global_load_lds((AS1 void*)g, (AS3 void*)l, 16, 0, 0);
}

__device__ __forceinline__ float exp2_(float x) {
#if __has_builtin(__builtin_amdgcn_exp2f)
  return __builtin_amdgcn_exp2f(x);
#else
  return exp2f(x);
#endif
}

__device__ __forceinline__ u32 cvt_pk_bf16(float lo, float hi) {
  u32 r;
  asm("v_cvt_pk_bf16_f32 %0, %1, %2" : "=v"(r) : "v"(lo), "v"(hi));
  return r;
}

__device__ __forceinline__ void lane32_swap(u32& a, u32& b) {
#if __has_builtin(__builtin_amdgcn_permlane32_swap)
  v2i r = __builtin_amdgcn_permlane32_swap((int)a, (int)b, false, false);
  a = (u32)r.x;
  b = (u32)r.y;
#else
  u32 ta = (u32)__shfl_xor((int)a, 32);
  u32 tb = (u32)__shfl_xor((int)b, 32);
  bool hi = (threadIdx.x & 32) != 0;
  u32 na = hi ? tb : a;
  u32 nb = hi ? b : ta;
  a = na;
  b = nb;
#endif
}

__device__ __forceinline__ float cross32_reduce_sum(float x) {
  u32 a = __float_as_uint(x), b = a;
  lane32_swap(a, b);
  return __uint_as_float(a) + __uint_as_float(b);
}

__device__ __forceinline__ int xcd_swizzle(int bid, int nwg) {
  int q8 = nwg >> 3;
  return (bid & 7) * q8 + (bid >> 3);
}

// ---------------- cast fp32 -> bf16 ----------------
__global__ __launch_bounds__(256) void k_cast(const float* __restrict__ in,
                                              u16* __restrict__ out, int n4) {
  int i = blockIdx.x * 256 + threadIdx.x;
  if (i < n4) {
    float4 v = ((const float4*)in)[i];
    u64 pk = (u64)f2bf(v.x) | ((u64)f2bf(v.y) << 16) |
             ((u64)f2bf(v.z) << 32) | ((u64)f2bf(v.w) << 48);
    ((u64*)out)[i] = pk;
  }
}

// ------------- transpose+cast: in fp32 [R][C] -> out bf16 [C][R] -------------
__global__ __launch_bounds__(256) void k_transpose_cast(const float* __restrict__ in,
                                                        u16* __restrict__ out,
                                                        int R, int C) {
  __shared__ u16 tile[32][33];
  const int cb = blockIdx.x * 32, rb = blockIdx.y * 32;
  const int tx = threadIdx.x & 31;
  const int ty = threadIdx.x >> 5;
#pragma unroll
  for (int i = 0; i < 4; i++) {
    int r = ty + i * 8;
    tile[r][tx] = f2bf(in[(size_t)(rb + r) * C + cb + tx]);
  }
  __syncthreads();
#pragma unroll
  for (int i = 0; i < 4; i++) {
    int r2 = ty + i * 8;
    out[(size_t)(cb + r2) * R + rb + tx] = tile[tx][r2];
  }
}

// ---------------- concat 3 bias vectors ----------------
__global__ __launch_bounds__(256) void k_concat3(const float* __restrict__ a,
                                                 const float* __restrict__ b,
                                                 const float* __restrict__ c,
                                                 float* __restrict__ out) {
  int i = blockIdx.x * 256 + threadIdx.x;
  if (i < 3072) out[i] = i < 1024 ? a[i] : (i < 2048 ? b[i - 1024] : c[i - 2048]);
}

enum { EPI_F32 = 0, EPI_GELU = 1, EPI_QKV3 = 2 };

// ======== 256x256 8-wave BK=64 deep-pipelined GEMM (full K), XCD-swizzled ========
template <int EPI>
__global__ __launch_bounds__(512) void k_gemm256(const u16* __restrict__ A,
                                                 const u16* __restrict__ Bt,
                                                 const float* __restrict__ bias,
                                                 void* __restrict__ Cout,
                                                 int N, int K, int nx) {
  __shared__ __align__(16) u16 smem[65536];  // 128 KiB
  const int tid = threadIdx.x;
  const int wid = tid >> 6, lane = tid & 63;
  const int lrow = lane & 15, lgrp = lane >> 4;
  const int wr = wid >> 2, wc = wid & 3;
  const int swz = xcd_swizzle(blockIdx.x, gridDim.x);
  const int mrow = (swz / nx) * 256, ncol = (swz % nx) * 256;

  const int srow = tid >> 3;
  const int sgd = tid & 7;
  const int gsw = (sgd ^ (srow & 7)) << 3;
  const u16* aS0 = A + (size_t)(mrow + srow) * K + gsw;
  const u16* bS0 = Bt + (size_t)(ncol + srow) * K + gsw;
  const int T = K >> 6;

  auto stageA = [&](int t, int b) {
    u16* dst = smem + b * 32768 + wid * 512;
    const u16* s = aS0 + t * 64;
#pragma unroll
    for (int c = 0; c < 4; ++c) gload_lds16(s + (size_t)c * 64 * K, dst + c * 4096);
  };
  auto stageB = [&](int t, int b) {
    u16* dst = smem + b * 32768 + 16384 + wid * 512;
    const u16* s = bS0 + t * 64;
#pragma unroll
    for (int c = 0; c < 4; ++c) gload_lds16(s + (size_t)c * 64 * K, dst + c * 4096);
  };

  f32x4 acc[8][4];
#pragma unroll
  for (int m = 0; m < 8; ++m)
#pragma unroll
    for (int n = 0; n < 4; ++n) acc[m][n] = (f32x4){0.f, 0.f, 0.f, 0.f};

  stageA(0, 0);
  stageB(0, 0);
  asm volatile("s_waitcnt vmcnt(0)" ::: "memory");
  __builtin_amdgcn_s_barrier();

  const int arow_base = wr * 128 + lrow;
  const int brow_base = wc * 64 + lrow;
  const int aswz = lrow & 7;

  for (int t = 0; t < T; ++t) {
    const int cb = (t & 1) * 32768;
    const u16* Abuf = smem + cb;
    const u16* Bbuf = smem + cb + 16384;
    bf16x8 af[4][2], bfr[4][2];
#pragma unroll
    for (int m = 0; m < 4; ++m)
#pragma unroll
      for (int ks = 0; ks < 2; ++ks)
        af[m][ks] = *(const bf16x8*)(Abuf + (arow_base + m * 16) * 64 +
                                     (((ks * 4 + lgrp) ^ aswz) << 3));
#pragma unroll
    for (int n = 0; n < 4; ++n)
#pragma unroll
      for (int ks = 0; ks < 2; ++ks)
        bfr[n][ks] = *(const bf16x8*)(Bbuf + (brow_base + n * 16) * 64 +
                                      (((ks * 4 + lgrp) ^ aswz) << 3));
    if (t + 1 < T) stageA(t + 1, (t + 1) & 1);
    __builtin_amdgcn_s_barrier();
    __builtin_amdgcn_s_setprio(1);
#pragma unroll
    for (int m = 0; m < 4; ++m)
#pragma unroll
      for (int n = 0; n < 2; ++n)
#pragma unroll
        for (int ks = 0; ks < 2; ++ks)
          acc[m][n] = __builtin_amdgcn_mfma_f32_16x16x32_bf16(af[m][ks], bfr[n][ks],
                                                              acc[m][n], 0, 0, 0);
    __builtin_amdgcn_s_setprio(0);
    if (t + 1 < T) stageB(t + 1, (t + 1) & 1);
    __builtin_amdgcn_s_barrier();
    __builtin_amdgcn_s_setprio(1);
#pragma unroll
    for (int m = 0; m < 4; ++m)
#pragma unroll
      for (int n = 2; n < 4; ++n)
#pragma unroll
        for (int ks = 0; ks < 2; ++ks)
          acc[m][n] = __builtin_amdgcn_mfma_f32_16x16x32_bf16(af[m][ks], bfr[n][ks],
                                                              acc[m][n], 0, 0, 0);
    __builtin_amdgcn_s_setprio(0);
#pragma unroll
    for (int m = 0; m < 4; ++m)
#pragma unroll
      for (int ks = 0; ks < 2; ++ks)
        af[m][ks] = *(const bf16x8*)(Abuf + (arow_base + (m + 4) * 16) * 64 +
                                     (((ks * 4 + lgrp) ^ aswz) << 3));
    __builtin_amdgcn_s_barrier();
    __builtin_amdgcn_s_setprio(1);
#pragma unroll
    for (int m = 0; m < 4; ++m)
#pragma unroll
      for (int n = 0; n < 2; ++n)
#pragma unroll
        for (int ks = 0; ks < 2; ++ks)
          acc[m + 4][n] = __builtin_amdgcn_mfma_f32_16x16x32_bf16(af[m][ks], bfr[n][ks],
                                                                  acc[m + 4][n], 0, 0, 0);
    __builtin_amdgcn_s_setprio(0);
    __builtin_amdgcn_s_barrier();
    __builtin_amdgcn_s_setprio(1);
#pragma unroll
    for (int m = 0; m < 4; ++m)
#pragma unroll
      for (int n = 2; n < 4; ++n)
#pragma unroll
        for (int ks = 0; ks < 2; ++ks)
          acc[m + 4][n] = __builtin_amdgcn_mfma_f32_16x16x32_bf16(af[m][ks], bfr[n][ks],
                                                                  acc[m + 4][n], 0, 0, 0);
    __builtin_amdgcn_s_setprio(0);
    if (t + 1 < T) {
      asm volatile("s_waitcnt vmcnt(0)" ::: "memory");
      __builtin_amdgcn_s_barrier();
      __builtin_amdgcn_sched_barrier(0);
    }
  }

#pragma unroll
  for (int m = 0; m < 8; ++m) {
#pragma unroll
    for (int n = 0; n < 4; ++n) {
      const int row0 = mrow + wr * 128 + m * 16 + lgrp * 4;
      const int col = ncol + wc * 64 + n * 16 + lrow;
      f32x4 v = acc[m][n];
      if constexpr (EPI == EPI_GELU) {
        const float bv = bias[col];
        u16* C = (u16*)Cout;
#pragma unroll
        for (int r = 0; r < 4; r++) {
          float xg = v[r] + bv;
          float gl = 0.5f * xg * (1.0f + erff(xg * 0.70710678118654752f));
          C[(size_t)(row0 + r) * N + col] = f2bf(gl);
        }
      } else if constexpr (EPI == EPI_QKV3) {
        const float bv = bias[col];
        char* wsb = (char*)Cout;
        const int seg = col >> 10, cc = col & 1023;
        const int h = cc >> 6, d = cc & 63;
        if (seg < 2) {
          u16* dst = (u16*)(wsb + (seg == 0 ? OFF_QB : OFF_KB));
#pragma unroll
          for (int r = 0; r < 4; r++) {
            const int row = row0 + r;
            const int b = row >> 11, s = row & 2047;
            dst[((size_t)(b * HH + h) * SS + s) * HD + d] = f2bf(v[r] + bv);
          }
        } else {
          u16* Vt = (u16*)(wsb + OFF_VT);
          const int b = row0 >> 11, s = row0 & 2047;
          u64 pk = (u64)f2bf(v[0] + bv) | ((u64)f2bf(v[1] + bv) << 16) |
                   ((u64)f2bf(v[2] + bv) << 32) | ((u64)f2bf(v[3] + bv) << 48);
          size_t addr = ((size_t)(b * HH + h) * (SS / 64) + (s >> 6)) * 4096 +
                        (size_t)d * 64 + (s & 63);
          *(u64*)&Vt[addr] = pk;
        }
      } else {
        const float bv = bias[col];
        float* C = (float*)Cout;
#pragma unroll
        for (int r = 0; r < 4; r++) C[(size_t)(row0 + r) * N + col] = v[r] + bv;
      }
    }
  }
}

// ======== 256x128 8-wave BK=64 GEMM, split-K, bf16 partial output ========
__global__ __launch_bounds__(512) void k_gemmMN(const u16* __restrict__ A,
                                                const u16* __restrict__ Bt,
                                                const float* __restrict__ bias,
                                                u16* __restrict__ Cout,
                                                int N, int Ksub, int stride,
                                                size_t zoff, int nx, int ny) {
  __shared__ __align__(16) u16 smem[49152];  // 96 KiB
  const int tid = threadIdx.x;
  const int wid = tid >> 6, lane = tid & 63;
  const int lrow = lane & 15, lgrp = lane >> 4;
  const int wr = wid >> 2, wc = wid & 3;
  const int swz = xcd_swizzle(blockIdx.x, gridDim.x);
  const int bx = swz % nx;
  const int by = (swz / nx) % ny;
  const int bz = swz / (nx * ny);
  const int mrow = by * 256, ncol = bx * 128;

  const int srow = tid >> 3;
  const int sgd = tid & 7;
  const int gsw = (sgd ^ (srow & 7)) << 3;
  const u16* aS0 = A + (size_t)(mrow + srow) * stride + (size_t)bz * Ksub + gsw;
  const u16* bS0 = Bt + (size_t)(ncol + srow) * stride + (size_t)bz * Ksub + gsw;
  const int T = Ksub >> 6;

  auto stageA = [&](int t, int b) {
    u16* dst = smem + b * 24576 + wid * 512;
    const u16* s = aS0 + t * 64;
#pragma unroll
    for (int c = 0; c < 4; ++c) gload_lds16(s + (size_t)c * 64 * stride, dst + c * 4096);
  };
  auto stageB = [&](int t, int b) {
    u16* dst = smem + b * 24576 + 16384 + wid * 512;
    const u16* s = bS0 + t * 64;
#pragma unroll
    for (int c = 0; c < 2; ++c) gload_lds16(s + (size_t)c * 64 * stride, dst + c * 4096);
  };

  f32x4 acc[8][2];
#pragma unroll
  for (int m = 0; m < 8; ++m)
#pragma unroll
    for (int n = 0; n < 2; ++n) acc[m][n] = (f32x4){0.f, 0.f, 0.f, 0.f};

  stageA(0, 0);
  stageB(0, 0);
  asm volatile("s_waitcnt vmcnt(0)" ::: "memory");
  __builtin_amdgcn_s_barrier();

  const int arow_base = wr * 128 + lrow;
  const int brow_base = wc * 32 + lrow;
  const int aswz = lrow & 7;

  for (int t = 0; t < T; ++t) {
    const int cb = (t & 1) * 24576;
    const u16* Abuf = smem + cb;
    const u16* Bbuf = smem + cb + 16384;
    bf16x8 af[4][2], bfr[2][2];
#pragma unroll
    for (int m = 0; m < 4; ++m)
#pragma unroll
      for (int ks = 0; ks < 2; ++ks)
        af[m][ks] = *(const bf16x8*)(Abuf + (arow_base + m * 16) * 64 +
                                     (((ks * 4 + lgrp) ^ aswz) << 3));
#pragma unroll
    for (int n = 0; n < 2; ++n)
#pragma unroll
      for (int ks = 0; ks < 2; ++ks)
        bfr[n][ks] = *(const bf16x8*)(Bbuf + (brow_base + n * 16) * 64 +
                                      (((ks * 4 + lgrp) ^ aswz) << 3));
    if (t + 1 < T) stageA(t + 1, (t + 1) & 1);
    __builtin_amdgcn_s_barrier();
    __builtin_amdgcn_s_setprio(1);
#pragma unroll
    for (int m = 0; m < 4; ++m)
#pragma unroll
      for (int ks = 0; ks < 2; ++ks)
        acc[m][0] = __builtin_amdgcn_mfma_f32_16x16x32_bf16(af[m][ks], bfr[0][ks],
                                                            acc[m][0], 0, 0, 0);
    __builtin_amdgcn_s_setprio(0);
    if (t + 1 < T) stageB(t + 1, (t + 1) & 1);
    __builtin_amdgcn_s_barrier();
    __builtin_amdgcn_s_setprio(1);
#pragma unroll
    for (int m = 0; m < 4; ++m)
#pragma unroll
      for (int ks = 0; ks < 2; ++ks)
        acc[m][1] = __builtin_amdgcn_mfma_f32_16x16x32_bf16(af[m][ks], bfr[1][ks],
                                                            acc[m][1], 0, 0, 0);
    __builtin_amdgcn_s_setprio(0);
#pragma unroll
    for (int m = 0; m < 4; ++m)
#pragma unroll
      for (int ks = 0; ks < 2; ++ks)
        af[m][ks] = *(const bf16x8*)(Abuf + (arow_base + (m + 4) * 16) * 64 +
                                     (((ks * 4 + lgrp) ^ aswz) << 3));
    __builtin_amdgcn_s_barrier();
    __builtin_amdgcn_s_setprio(1);
#pragma unroll
    for (int m = 0; m < 4; ++m)
#pragma unroll
      for (int ks = 0; ks < 2; ++ks)
        acc[m + 4][0] = __builtin_amdgcn_mfma_f32_16x16x32_bf16(af[m][ks], bfr[0][ks],
                                                                acc[m + 4][0], 0, 0, 0);
    __builtin_amdgcn_s_setprio(0);
    __builtin_amdgcn_s_barrier();
    __builtin_amdgcn_s_setprio(1);
#pragma unroll
    for (int m = 0; m < 4; ++m)
#pragma unroll
      for (int ks = 0; ks < 2; ++ks)
        acc[m + 4][1] = __builtin_amdgcn_mfma_f32_16x16x32_bf16(af[m][ks], bfr[1][ks],
                                                                acc[m + 4][1], 0, 0, 0);
    __builtin_amdgcn_s_setprio(0);
    if (t + 1 < T) {
      asm volatile("s_waitcnt vmcnt(0)" ::: "memory");
      __builtin_amdgcn_s_barrier();
      __builtin_amdgcn_sched_barrier(0);
    }
  }

  u16* C = Cout + (size_t)bz * zoff;
#pragma unroll
  for (int m = 0; m < 8; ++m) {
#pragma unroll
    for (int n = 0; n < 2; ++n) {
      const int row0 = mrow + wr * 128 + m * 16 + lgrp * 4;
      const int col = ncol + wc * 32 + n * 16 + lrow;
      const float bv = (bz == 0) ? bias[col] : 0.0f;
      f32x4 v = acc[m][n];
#pragma unroll
      for (int r = 0; r < 4; r++) C[(size_t)(row0 + r) * N + col] = f2bf(v[r] + bv);
    }
  }
}

// ---------------- flash attention, KV-split=4, KVBLK=64, fixed-C softmax ----------------
__global__ __launch_bounds__(256) void k_attn_split(const u16* __restrict__ Q,
                                                    const u16* __restrict__ K,
                                                    const u16* __restrict__ Vt,
                                                    u16* __restrict__ Opart,
                                                    float* __restrict__ lpart) {
  __shared__ __align__(16) u16 Kl[2][4096];
  __shared__ __align__(16) u16 Vl[2][4096];
  const int tid = threadIdx.x, wid = tid >> 6, lane = tid & 63;
  const int ql = lane & 31, hi = lane >> 5;
  const int bx = blockIdx.x;
  const int split = bx >> 9, bh = (bx >> 4) & 31, qblk = bx & 15;
  const int qbase = qblk * 128 + wid * 32;
  const int kvS = split * 512;
  const u16* Qh = Q + (size_t)bh * SS * HD;
  const u16* Kh = K + (size_t)bh * SS * HD;
  const u16* Vh = Vt + (size_t)bh * SS * HD;

  const int lrow3 = lane >> 3;
  const int lin = lrow3 * 128 + ((((lane & 7) << 4)) ^ (lrow3 << 4));
  const int kswz = (ql & 7) << 4;

  auto stage = [&](int kv0, int bufi) {
    const char* Ks = (const char*)Kh + (size_t)kv0 * 128 + wid * 2048 + lin;
    const char* Vs = (const char*)Vh + ((size_t)(kv0 >> 6)) * 8192 + wid * 2048 + lin;
    char* kd = (char*)&Kl[bufi][0] + wid * 2048;
    char* vd = (char*)&Vl[bufi][0] + wid * 2048;
    gload_lds16(Ks, kd);
    gload_lds16(Ks + 1024, kd + 1024);
    gload_lds16(Vs, vd);
    gload_lds16(Vs + 1024, vd + 1024);
  };

  bf16x8 qf[4];
#pragma unroll
  for (int j = 0; j < 4; j++)
    qf[j] = *(const bf16x8*)&Qh[(size_t)(qbase + ql) * HD + j * 16 + hi * 8];

  f32x16 oacc0, oacc1;
#pragma unroll
  for (int r = 0; r < 16; r++) { oacc0[r] = 0.f; oacc1[r] = 0.f; }
  float lsum = 0.f;
  const float cs = 0.125f * 1.44269504f;
  const float CSHIFT = 24.0f;

  auto tileC = [&](int bufi, int tt) {
    const char* Kb = (const char*)&Kl[bufi][0];
    const char* Vb = (const char*)&Vl[bufi][0];
    bf16x8 kf[4];
#pragma unroll
    for (int j = 0; j < 4; j++)
      kf[j] = *(const bf16x8*)(Kb + (tt * 32 + ql) * 128 + ((j * 32 + hi * 16) ^ kswz));

    f32x16 s;
#pragma unroll
    for (int r = 0; r < 16; r++) s[r] = 0.f;
#pragma unroll
    for (int j = 0; j < 4; j++)
      s = __builtin_amdgcn_mfma_f32_32x32x16_bf16(kf[j], qf[j], s, 0, 0, 0);

    float p[16];
#pragma unroll
    for (int r = 0; r < 16; r++) p[r] = exp2_(fmaf(s[r], cs, -CSHIFT));
    float t0 = (p[0] + p[1]) + (p[2] + p[3]);
    float t1 = (p[4] + p[5]) + (p[6] + p[7]);
    float t2 = (p[8] + p[9]) + (p[10] + p[11]);
    float t3 = (p[12] + p[13]) + (p[14] + p[15]);
    lsum += cross32_reduce_sum((t0 + t1) + (t2 + t3));

    u32 w01 = cvt_pk_bf16(p[0], p[1]), w23 = cvt_pk_bf16(p[2], p[3]);
    u32 w45 = cvt_pk_bf16(p[4], p[5]), w67 = cvt_pk_bf16(p[6], p[7]);
    u32 w89 = cvt_pk_bf16(p[8], p[9]), wab = cvt_pk_bf16(p[10], p[11]);
    u32 wcd = cvt_pk_bf16(p[12], p[13]), wef = cvt_pk_bf16(p[14], p[15]);
    lane32_swap(w01, w45);
    lane32_swap(w23, w67);
    lane32_swap(w89, wcd);
    lane32_swap(wab, wef);
    union { u32 w[4]; bf16x8 v; } f0, f1;
    f0.w[0] = w01; f0.w[1] = w23; f0.w[2] = w45; f0.w[3] = w67;
    f1.w[0] = w89; f1.w[1] = wab; f1.w[2] = wcd; f1.w[3] = wef;

    bf16x8 vf[4];
#pragma unroll
    for (int u = 0; u < 4; u++)
      vf[u] = *(const bf16x8*)(Vb + ((u >> 1) * 32 + ql) * 128 +
                               ((tt * 64 + (u & 1) * 32 + hi * 16) ^ kswz));

    oacc0 = __builtin_amdgcn_mfma_f32_32x32x16_bf16(vf[0], f0.v, oacc0, 0, 0, 0);
    oacc0 = __builtin_amdgcn_mfma_f32_32x32x16_bf16(vf[1], f1.v, oacc0, 0, 0, 0);
    oacc1 = __builtin_amdgcn_mfma_f32_32x32x16_bf16(vf[2], f0.v, oacc1, 0, 0, 0);
    oacc1 = __builtin_amdgcn_mfma_f32_32x32x16_bf16(vf[3], f1.v, oacc1, 0, 0, 0);
  };

  stage(kvS, 0);
  __syncthreads();
  int cur = 0;
  for (int it = 0; it < 8; ++it) {
    if (it + 1 < 8) stage(kvS + (it + 1) * 64, cur ^ 1);
    tileC(cur, 0);
    tileC(cur, 1);
    __syncthreads();
    cur ^= 1;
  }

  const int rowidx = bh * SS + qbase + ql;
  u16* Orow = Opart + ((size_t)split * 32 * SS + rowidx) * HD;
  auto storeAcc = [&](const f32x16& a, int dbase) {
#pragma unroll
    for (int t = 0; t < 4; t++) {
      u64 pk = (u64)f2bf(a[4 * t]) | ((u64)f2bf(a[4 * t + 1]) << 16) |
               ((u64)f2bf(a[4 * t + 2]) << 32) | ((u64)f2bf(a[4 * t + 3]) << 48);
      *(u64*)&Orow[dbase + 4 * hi + 8 * t] = pk;
    }
  };
  storeAcc(oacc0, 0);
  storeAcc(oacc1, 32);
  if (hi == 0) lpart[(size_t)split * 32 * SS + rowidx] = lsum;
}

// ---------------- merge the 4 KV-split partials (plain sums) -> bf16 O ----------------
__global__ __launch_bounds__(256) void k_attn_merge(const u16* __restrict__ Opart,
                                                    const float* __restrict__ lpart,
                                                    u16* __restrict__ O) {
  const int g = blockIdx.x * 256 + threadIdx.x;
  const int row = g >> 4, dseg = g & 15;
  float denom = 0.f;
#pragma unroll
  for (int s = 0; s < 4; s++) denom += lpart[(size_t)s * 32 * SS + row];
  const float inv = 1.0f / denom;
  float acc[4] = {0.f, 0.f, 0.f, 0.f};
#pragma unroll
  for (int s = 0; s < 4; s++) {
    u64 pk = *(const u64*)&Opart[(((size_t)s * 32 * SS + row) * HD) + dseg * 4];
#pragma unroll
    for (int k = 0; k < 4; k++) acc[k] += bf2f((u16)(pk >> (16 * k)));
  }
  const int bh = row >> 11, s2 = row & 2047;
  const int bb = bh >> 4, h = bh & 15;
  u64 pk = (u64)f2bf(acc[0] * inv) | ((u64)f2bf(acc[1] * inv) << 16) |
           ((u64)f2bf(acc[2] * inv) << 32) | ((u64)f2bf(acc[3] * inv) << 48);
  *(u64*)&O[((size_t)(bb * SS + s2) * DM) + h * HD + dseg * 4] = pk;
}

// ---------------- fused residual(2-way) + layernorm ----------------
// XBF: X input bf16 (else f32). Y0/Y1 are bf16 partials. WB: write bf16 (else f32).
template <bool XBF, bool WB>
__global__ __launch_bounds__(256) void k_res_ln(const void* __restrict__ Xv,
                                                const u16* __restrict__ Y0,
                                                const u16* __restrict__ Y1,
                                                const float* __restrict__ gw,
                                                const float* __restrict__ bw,
                                                float* __restrict__ outf,
                                                u16* __restrict__ outb) {
  const int row = blockIdx.x, t = threadIdx.x;
  float x0, x1, x2, x3;
  if constexpr (XBF) {
    u64 pk = ((const u64*)Xv)[(size_t)row * 256 + t];
    x0 = bf2f((u16)pk);
    x1 = bf2f((u16)(pk >> 16));
    x2 = bf2f((u16)(pk >> 32));
    x3 = bf2f((u16)(pk >> 48));
  } else {
    float4 xv = ((const float4*)Xv)[(size_t)row * 256 + t];
    x0 = xv.x; x1 = xv.y; x2 = xv.z; x3 = xv.w;
  }
  const u64 p0 = ((const u64*)Y0)[(size_t)row * 256 + t];
  const u64 p1 = ((const u64*)Y1)[(size_t)row * 256 + t];
  float v0 = x0 + bf2f((u16)p0) + bf2f((u16)p1);
  float v1 = x1 + bf2f((u16)(p0 >> 16)) + bf2f((u16)(p1 >> 16));
  float v2 = x2 + bf2f((u16)(p0 >> 32)) + bf2f((u16)(p1 >> 32));
  float v3 = x3 + bf2f((u16)(p0 >> 48)) + bf2f((u16)(p1 >> 48));
  float s = v0 + v1 + v2 + v3;
  float s2 = v0 * v0 + v1 * v1 + v2 * v2 + v3 * v3;
#pragma unroll
  for (int off = 32; off >= 1; off >>= 1) {
    s += __shfl_down(s, off);
    s2 += __shfl_down(s2, off);
  }
  __shared__ float ps[4], ps2[4];
  const int wid = t >> 6, lane = t & 63;
  if (lane == 0) { ps[wid] = s; ps2[wid] = s2; }
  __syncthreads();
  const float ts = ps[0] + ps[1] + ps[2] + ps[3];
  const float ts2 = ps2[0] + ps2[1] + ps2[2] + ps2[3];
  const float mu = ts * (1.f / 1024.f);
  const float rs = rsqrtf(ts2 * (1.f / 1024.f) - mu * mu + 1e-5f);
  const float4 g4 = ((const float4*)gw)[t];
  const float4 b4 = ((const float4*)bw)[t];
  float o0 = (v0 - mu) * rs * g4.x + b4.x;
  float o1 = (v1 - mu) * rs * g4.y + b4.y;
  float o2 = (v2 - mu) * rs * g4.z + b4.z;
  float o3 = (v3 - mu) * rs * g4.w + b4.w;
  if constexpr (WB) {
    u64 pk = (u64)f2bf(o0) | ((u64)f2bf(o1) << 16) | ((u64)f2bf(o2) << 32) |
             ((u64)f2bf(o3) << 48);
    ((u64*)(outb + (size_t)row * DM))[t] = pk;
  } else {
    ((float4*)(outf + (size_t)row * DM))[t] = make_float4(o0, o1, o2, o3);
  }
}

extern "C" void kernel_launch(void* const* d_in, const int* in_sizes, int n_in,
                              void* d_out, int out_size, void* d_ws, size_t ws_size,
                              hipStream_t stream) {
  const float* x = (const float*)d_in[0];
  const float* Wq = (const float*)d_in[1];
  const float* bq = (const float*)d_in[2];
  const float* Wk = (const float*)d_in[3];
  const float* bk = (const float*)d_in[4];
  const float* Wv = (const float*)d_in[5];
  const float* bv = (const float*)d_in[6];
  const float* Wo = (const float*)d_in[7];
  const float* bo = (const float*)d_in[8];
  const float* g1 = (const float*)d_in[9];
  const float* b1 = (const float*)d_in[10];
  const float* g2 = (const float*)d_in[11];
  const float* b2 = (const float*)d_in[12];
  const float* W1 = (const float*)d_in[13];
  const float* bf1 = (const float*)d_in[14];
  const float* W2 = (const float*)d_in[15];
  const float* bf2 = (const float*)d_in[16];
  float* out = (float*)d_out;

  if (ws_size < 92 * MiB) return;
  char* ws = (char*)d_ws;
  u16* WqkvT = (u16*)(ws + OFF_WQKVT);
  u16* WoT = (u16*)(ws + OFF_WOT);
  u16* W1T = (u16*)(ws + OFF_W1T);
  u16* W2T = (u16*)(ws + OFF_W2T);
  u16* xb = (u16*)(ws + OFF_XB);
  u16* Qb = (u16*)(ws + OFF_QB);
  u16* Kb = (u16*)(ws + OFF_KB);
  u16* Vt = (u16*)(ws + OFF_VT);
  u16* Ob = (u16*)(ws + OFF_XB);
  u16* Opart = (u16*)(ws + OFF_OPART);
  float* lpart = (float*)(ws + OFF_ML);
  float* bqkv = (float*)(ws + OFF_BQKV);
  u16* attn0 = (u16*)(ws + OFF_ATTN0);
  u16* attn1 = (u16*)(ws + OFF_ATTN1);
  u16* hb = (u16*)(ws + OFF_HB);
  u16* f1 = (u16*)(ws + OFF_F1);
  u16* ffn0 = (u16*)(ws + OFF_FFN0);
  u16* ffn1 = (u16*)(ws + OFF_FFN1);

  k_cast<<<4096, 256, 0, stream>>>(x, xb, TT * DM / 4);
  k_transpose_cast<<<dim3(32, 32), 256, 0, stream>>>(Wq, WqkvT, DM, DM);
  k_transpose_cast<<<dim3(32, 32), 256, 0, stream>>>(Wk, WqkvT + 1024 * 1024, DM, DM);
  k_transpose_cast<<<dim3(32, 32), 256, 0, stream>>>(Wv, WqkvT + 2048 * 1024, DM, DM);
  k_transpose_cast<<<dim3(32, 32), 256, 0, stream>>>(Wo, WoT, DM, DM);
  k_transpose_cast<<<dim3(128, 32), 256, 0, stream>>>(W1, W1T, DM, DFF);
  k_transpose_cast<<<dim3(32, 128), 256, 0, stream>>>(W2, W2T, DFF, DM);
  k_concat3<<<12, 256, 0, stream>>>(bq, bk, bv, bqkv);

  // fused QKV projection: 256^2 tiles, grid 12x16 = 192
  k_gemm256<EPI_QKV3><<<192, 512, 0, stream>>>(xb, WqkvT, bqkv, ws, 3072, DM, 12);

  // flash attention: split=4, grid 2048, KVBLK=64
  k_attn_split<<<2048, 256, 0, stream>>>(Qb, Kb, Vt, Opart, lpart);
  k_attn_merge<<<4096, 256, 0, stream>>>(Opart, lpart, Ob);

  // Wo projection: 256x128 tiles, split-K=2, bf16 partials at ATTN0/ATTN1
  k_gemmMN<<<256, 512, 0, stream>>>(Ob, WoT, bo, attn0, DM, DM / 2, DM,
                                    (OFF_ATTN1 - OFF_ATTN0) / 2, 8, 16);
  k_res_ln<false, true><<<4096, 256, 0, stream>>>(x, attn0, attn1, g1, b1,
                                                  nullptr, hb);

  // FFN1: 256^2 tiles, grid 16x16 = 256
  k_gemm256<EPI_GELU><<<256, 512, 0, stream>>>(hb, W1T, bf1, f1, DFF, DM, 16);

  // FFN2: 256x128 tiles, split-K=2, bf16 partials at FFN0/FFN1
  k_gemmMN<<<256, 512, 0, stream>>>(f1, W2T, bf2, ffn0, DM, DFF / 2, DFF,
                                    (OFF_FFN1 - OFF_FFN0) / 2, 8, 16);
  k_res_ln<true, false><<<4096, 256, 0, stream>>>(hb, ffn0, ffn1, g2, b2, out, nullptr);
}

// Round 16
// 239.671 us; speedup vs baseline: 1.1444x; 1.0522x over previous
//
#include <hip/hip_runtime.h>
#include <cstdint>
#include <cmath>

typedef unsigned short u16;
typedef unsigned int u32;
typedef unsigned long long u64;
typedef __bf16 bf16x8 __attribute__((ext_vector_type(8)));
typedef float f32x4 __attribute__((ext_vector_type(4)));
typedef float f32x16 __attribute__((ext_vector_type(16)));
typedef int v2i __attribute__((ext_vector_type(2)));

#define AS1 __attribute__((address_space(1)))
#define AS3 __attribute__((address_space(3)))

static constexpr int DM = 1024, DFF = 4096, SS = 2048, HH = 16, HD = 64, TT = 4096;
static constexpr size_t MiB = (size_t)1 << 20;
// workspace map (bytes) — live-range audited (r15):
static constexpr size_t OFF_WQKVT = 0;
static constexpr size_t OFF_WOT = 6 * MiB;
static constexpr size_t OFF_W1T = 8 * MiB;
static constexpr size_t OFF_W2T = 16 * MiB;
static constexpr size_t OFF_XB = 24 * MiB;
static constexpr size_t OFF_QB = 32 * MiB;
static constexpr size_t OFF_KB = 40 * MiB;
static constexpr size_t OFF_VT = 48 * MiB;
static constexpr size_t OFF_OPART = 56 * MiB;
static constexpr size_t OFF_ML = 88 * MiB;
static constexpr size_t OFF_BQKV = 90 * MiB;
static constexpr size_t OFF_ATTN0 = 32 * MiB;  // bf16 partial, 8 MiB
static constexpr size_t OFF_ATTN1 = 40 * MiB;  // bf16 partial, 8 MiB
static constexpr size_t OFF_HB = 48 * MiB;     // bf16 h, 8 MiB
static constexpr size_t OFF_F1 = 56 * MiB;     // bf16 gelu out, 32 MiB
static constexpr size_t OFF_FFN0 = 24 * MiB;   // bf16 partial, 8 MiB
static constexpr size_t OFF_FFN1 = 32 * MiB;   // bf16 partial, 8 MiB

__device__ __forceinline__ u16 f2bf(float f) {
  union { float f; unsigned u; } c; c.f = f;
  unsigned r = c.u + 0x7fffu + ((c.u >> 16) & 1u);
  return (u16)(r >> 16);
}
__device__ __forceinline__ float bf2f(u16 h) {
  union { unsigned u; float f; } c; c.u = ((u32)h) << 16;
  return c.f;
}

__device__ __forceinline__ void gload_lds16(const void* g, void* l) {
  __builtin_amdgcn_global_load_lds((AS1 void*)g, (AS3 void*)l, 16, 0, 0);
}

__device__ __forceinline__ float exp2_(float x) {
#if __has_builtin(__builtin_amdgcn_exp2f)
  return __builtin_amdgcn_exp2f(x);
#else
  return exp2f(x);
#endif
}

__device__ __forceinline__ u32 cvt_pk_bf16(float lo, float hi) {
  u32 r;
  asm("v_cvt_pk_bf16_f32 %0, %1, %2" : "=v"(r) : "v"(lo), "v"(hi));
  return r;
}

__device__ __forceinline__ void lane32_swap(u32& a, u32& b) {
#if __has_builtin(__builtin_amdgcn_permlane32_swap)
  v2i r = __builtin_amdgcn_permlane32_swap((int)a, (int)b, false, false);
  a = (u32)r.x;
  b = (u32)r.y;
#else
  u32 ta = (u32)__shfl_xor((int)a, 32);
  u32 tb = (u32)__shfl_xor((int)b, 32);
  bool hi = (threadIdx.x & 32) != 0;
  u32 na = hi ? tb : a;
  u32 nb = hi ? b : ta;
  a = na;
  b = nb;
#endif
}

__device__ __forceinline__ float cross32_reduce_sum(float x) {
  u32 a = __float_as_uint(x), b = a;
  lane32_swap(a, b);
  return __uint_as_float(a) + __uint_as_float(b);
}

__device__ __forceinline__ int xcd_swizzle(int bid, int nwg) {
  int q8 = nwg >> 3;
  return (bid & 7) * q8 + (bid >> 3);
}

// ======== fused prep: cast x, transpose-cast 6 weights, concat biases ========
// blocks 0-4095: cast x -> xb
// 4096-8191: Wq/Wk/Wv/Wo 32x32-tile transpose (1024 tiles each)
// 8192-12287: W1 (R=1024,C=4096); 12288-16383: W2 (R=4096,C=1024); 16384: biases
__global__ __launch_bounds__(256) void k_prep(const float* __restrict__ x,
                                              const float* __restrict__ Wq,
                                              const float* __restrict__ Wk,
                                              const float* __restrict__ Wv,
                                              const float* __restrict__ Wo,
                                              const float* __restrict__ W1,
                                              const float* __restrict__ W2,
                                              const float* __restrict__ bq,
                                              const float* __restrict__ bk,
                                              const float* __restrict__ bv,
                                              char* __restrict__ ws) {
  const int blk = blockIdx.x;
  const int tid = threadIdx.x;
  if (blk < 4096) {  // cast x -> xb
    u16* out = (u16*)(ws + OFF_XB);
    int i = blk * 256 + tid;
    float4 v = ((const float4*)x)[i];
    u64 pk = (u64)f2bf(v.x) | ((u64)f2bf(v.y) << 16) |
             ((u64)f2bf(v.z) << 32) | ((u64)f2bf(v.w) << 48);
    ((u64*)out)[i] = pk;
    return;
  }
  if (blk == 16384) {  // concat biases
    float* out = (float*)(ws + OFF_BQKV);
#pragma unroll
    for (int it = 0; it < 12; ++it) {
      int i = it * 256 + tid;
      out[i] = i < 1024 ? bq[i] : (i < 2048 ? bk[i - 1024] : bv[i - 2048]);
    }
    return;
  }
  // transpose region
  const float* in;
  u16* out;
  int R, C, t;
  if (blk < 8192) {
    t = blk - 4096;
    const int w = t >> 10;  // 0..3
    t &= 1023;
    R = DM; C = DM;
    if (w == 0) { in = Wq; out = (u16*)(ws + OFF_WQKVT); }
    else if (w == 1) { in = Wk; out = (u16*)(ws + OFF_WQKVT) + 1024 * 1024; }
    else if (w == 2) { in = Wv; out = (u16*)(ws + OFF_WQKVT) + 2048 * 1024; }
    else { in = Wo; out = (u16*)(ws + OFF_WOT); }
  } else if (blk < 12288) {
    t = blk - 8192;
    R = DM; C = DFF;
    in = W1; out = (u16*)(ws + OFF_W1T);
  } else {
    t = blk - 12288;
    R = DFF; C = DM;
    in = W2; out = (u16*)(ws + OFF_W2T);
  }
  const int ntx = C >> 5;
  const int cb = (t % ntx) * 32, rb = (t / ntx) * 32;
  __shared__ u16 tile[32][33];
  const int tx = tid & 31;
  const int ty = tid >> 5;
#pragma unroll
  for (int i = 0; i < 4; i++) {
    int r = ty + i * 8;
    tile[r][tx] = f2bf(in[(size_t)(rb + r) * C + cb + tx]);
  }
  __syncthreads();
#pragma unroll
  for (int i = 0; i < 4; i++) {
    int r2 = ty + i * 8;
    out[(size_t)(cb + r2) * R + rb + tx] = tile[tx][r2];
  }
}

enum { EPI_F32 = 0, EPI_GELU = 1, EPI_QKV3 = 2 };

// ======== 256x256 8-wave BK=64 deep-pipelined GEMM (full K), XCD-swizzled ========
template <int EPI>
__global__ __launch_bounds__(512) void k_gemm256(const u16* __restrict__ A,
                                                 const u16* __restrict__ Bt,
                                                 const float* __restrict__ bias,
                                                 void* __restrict__ Cout,
                                                 int N, int K, int nx) {
  __shared__ __align__(16) u16 smem[65536];  // 128 KiB
  const int tid = threadIdx.x;
  const int wid = tid >> 6, lane = tid & 63;
  const int lrow = lane & 15, lgrp = lane >> 4;
  const int wr = wid >> 2, wc = wid & 3;
  const int swz = xcd_swizzle(blockIdx.x, gridDim.x);
  const int mrow = (swz / nx) * 256, ncol = (swz % nx) * 256;

  const int srow = tid >> 3;
  const int sgd = tid & 7;
  const int gsw = (sgd ^ (srow & 7)) << 3;
  const u16* aS0 = A + (size_t)(mrow + srow) * K + gsw;
  const u16* bS0 = Bt + (size_t)(ncol + srow) * K + gsw;
  const int T = K >> 6;

  auto stageA = [&](int t, int b) {
    u16* dst = smem + b * 32768 + wid * 512;
    const u16* s = aS0 + t * 64;
#pragma unroll
    for (int c = 0; c < 4; ++c) gload_lds16(s + (size_t)c * 64 * K, dst + c * 4096);
  };
  auto stageB = [&](int t, int b) {
    u16* dst = smem + b * 32768 + 16384 + wid * 512;
    const u16* s = bS0 + t * 64;
#pragma unroll
    for (int c = 0; c < 4; ++c) gload_lds16(s + (size_t)c * 64 * K, dst + c * 4096);
  };

  f32x4 acc[8][4];
#pragma unroll
  for (int m = 0; m < 8; ++m)
#pragma unroll
    for (int n = 0; n < 4; ++n) acc[m][n] = (f32x4){0.f, 0.f, 0.f, 0.f};

  stageA(0, 0);
  stageB(0, 0);
  asm volatile("s_waitcnt vmcnt(0)" ::: "memory");
  __builtin_amdgcn_s_barrier();

  const int arow_base = wr * 128 + lrow;
  const int brow_base = wc * 64 + lrow;
  const int aswz = lrow & 7;

  for (int t = 0; t < T; ++t) {
    const int cb = (t & 1) * 32768;
    const u16* Abuf = smem + cb;
    const u16* Bbuf = smem + cb + 16384;
    bf16x8 af[4][2], bfr[4][2];
#pragma unroll
    for (int m = 0; m < 4; ++m)
#pragma unroll
      for (int ks = 0; ks < 2; ++ks)
        af[m][ks] = *(const bf16x8*)(Abuf + (arow_base + m * 16) * 64 +
                                     (((ks * 4 + lgrp) ^ aswz) << 3));
#pragma unroll
    for (int n = 0; n < 4; ++n)
#pragma unroll
      for (int ks = 0; ks < 2; ++ks)
        bfr[n][ks] = *(const bf16x8*)(Bbuf + (brow_base + n * 16) * 64 +
                                      (((ks * 4 + lgrp) ^ aswz) << 3));
    if (t + 1 < T) stageA(t + 1, (t + 1) & 1);
    __builtin_amdgcn_s_barrier();
    __builtin_amdgcn_s_setprio(1);
#pragma unroll
    for (int m = 0; m < 4; ++m)
#pragma unroll
      for (int n = 0; n < 2; ++n)
#pragma unroll
        for (int ks = 0; ks < 2; ++ks)
          acc[m][n] = __builtin_amdgcn_mfma_f32_16x16x32_bf16(af[m][ks], bfr[n][ks],
                                                              acc[m][n], 0, 0, 0);
    __builtin_amdgcn_s_setprio(0);
    if (t + 1 < T) stageB(t + 1, (t + 1) & 1);
    __builtin_amdgcn_s_barrier();
    __builtin_amdgcn_s_setprio(1);
#pragma unroll
    for (int m = 0; m < 4; ++m)
#pragma unroll
      for (int n = 2; n < 4; ++n)
#pragma unroll
        for (int ks = 0; ks < 2; ++ks)
          acc[m][n] = __builtin_amdgcn_mfma_f32_16x16x32_bf16(af[m][ks], bfr[n][ks],
                                                              acc[m][n], 0, 0, 0);
    __builtin_amdgcn_s_setprio(0);
#pragma unroll
    for (int m = 0; m < 4; ++m)
#pragma unroll
      for (int ks = 0; ks < 2; ++ks)
        af[m][ks] = *(const bf16x8*)(Abuf + (arow_base + (m + 4) * 16) * 64 +
                                     (((ks * 4 + lgrp) ^ aswz) << 3));
    __builtin_amdgcn_s_barrier();
    __builtin_amdgcn_s_setprio(1);
#pragma unroll
    for (int m = 0; m < 4; ++m)
#pragma unroll
      for (int n = 0; n < 2; ++n)
#pragma unroll
        for (int ks = 0; ks < 2; ++ks)
          acc[m + 4][n] = __builtin_amdgcn_mfma_f32_16x16x32_bf16(af[m][ks], bfr[n][ks],
                                                                  acc[m + 4][n], 0, 0, 0);
    __builtin_amdgcn_s_setprio(0);
    __builtin_amdgcn_s_barrier();
    __builtin_amdgcn_s_setprio(1);
#pragma unroll
    for (int m = 0; m < 4; ++m)
#pragma unroll
      for (int n = 2; n < 4; ++n)
#pragma unroll
        for (int ks = 0; ks < 2; ++ks)
          acc[m + 4][n] = __builtin_amdgcn_mfma_f32_16x16x32_bf16(af[m][ks], bfr[n][ks],
                                                                  acc[m + 4][n], 0, 0, 0);
    __builtin_amdgcn_s_setprio(0);
    if (t + 1 < T) {
      asm volatile("s_waitcnt vmcnt(0)" ::: "memory");
      __builtin_amdgcn_s_barrier();
      __builtin_amdgcn_sched_barrier(0);
    }
  }

#pragma unroll
  for (int m = 0; m < 8; ++m) {
#pragma unroll
    for (int n = 0; n < 4; ++n) {
      const int row0 = mrow + wr * 128 + m * 16 + lgrp * 4;
      const int col = ncol + wc * 64 + n * 16 + lrow;
      f32x4 v = acc[m][n];
      if constexpr (EPI == EPI_GELU) {
        const float bv = bias[col];
        u16* C = (u16*)Cout;
#pragma unroll
        for (int r = 0; r < 4; r++) {
          float xg = v[r] + bv;
          float gl = 0.5f * xg * (1.0f + erff(xg * 0.70710678118654752f));
          C[(size_t)(row0 + r) * N + col] = f2bf(gl);
        }
      } else if constexpr (EPI == EPI_QKV3) {
        const float bv = bias[col];
        char* wsb = (char*)Cout;
        const int seg = col >> 10, cc = col & 1023;
        const int h = cc >> 6, d = cc & 63;
        if (seg < 2) {
          u16* dst = (u16*)(wsb + (seg == 0 ? OFF_QB : OFF_KB));
#pragma unroll
          for (int r = 0; r < 4; r++) {
            const int row = row0 + r;
            const int b = row >> 11, s = row & 2047;
            dst[((size_t)(b * HH + h) * SS + s) * HD + d] = f2bf(v[r] + bv);
          }
        } else {
          u16* Vt = (u16*)(wsb + OFF_VT);
          const int b = row0 >> 11, s = row0 & 2047;
          u64 pk = (u64)f2bf(v[0] + bv) | ((u64)f2bf(v[1] + bv) << 16) |
                   ((u64)f2bf(v[2] + bv) << 32) | ((u64)f2bf(v[3] + bv) << 48);
          size_t addr = ((size_t)(b * HH + h) * (SS / 64) + (s >> 6)) * 4096 +
                        (size_t)d * 64 + (s & 63);
          *(u64*)&Vt[addr] = pk;
        }
      } else {
        const float bv = bias[col];
        float* C = (float*)Cout;
#pragma unroll
        for (int r = 0; r < 4; r++) C[(size_t)(row0 + r) * N + col] = v[r] + bv;
      }
    }
  }
}

// ======== 256x128 8-wave BK=64 GEMM, split-K, bf16 partial output ========
__global__ __launch_bounds__(512) void k_gemmMN(const u16* __restrict__ A,
                                                const u16* __restrict__ Bt,
                                                const float* __restrict__ bias,
                                                u16* __restrict__ Cout,
                                                int N, int Ksub, int stride,
                                                size_t zoff, int nx, int ny) {
  __shared__ __align__(16) u16 smem[49152];  // 96 KiB
  const int tid = threadIdx.x;
  const int wid = tid >> 6, lane = tid & 63;
  const int lrow = lane & 15, lgrp = lane >> 4;
  const int wr = wid >> 2, wc = wid & 3;
  const int swz = xcd_swizzle(blockIdx.x, gridDim.x);
  const int bx = swz % nx;
  const int by = (swz / nx) % ny;
  const int bz = swz / (nx * ny);
  const int mrow = by * 256, ncol = bx * 128;

  const int srow = tid >> 3;
  const int sgd = tid & 7;
  const int gsw = (sgd ^ (srow & 7)) << 3;
  const u16* aS0 = A + (size_t)(mrow + srow) * stride + (size_t)bz * Ksub + gsw;
  const u16* bS0 = Bt + (size_t)(ncol + srow) * stride + (size_t)bz * Ksub + gsw;
  const int T = Ksub >> 6;

  auto stageA = [&](int t, int b) {
    u16* dst = smem + b * 24576 + wid * 512;
    const u16* s = aS0 + t * 64;
#pragma unroll
    for (int c = 0; c < 4; ++c) gload_lds16(s + (size_t)c * 64 * stride, dst + c * 4096);
  };
  auto stageB = [&](int t, int b) {
    u16* dst = smem + b * 24576 + 16384 + wid * 512;
    const u16* s = bS0 + t * 64;
#pragma unroll
    for (int c = 0; c < 2; ++c) gload_lds16(s + (size_t)c * 64 * stride, dst + c * 4096);
  };

  f32x4 acc[8][2];
#pragma unroll
  for (int m = 0; m < 8; ++m)
#pragma unroll
    for (int n = 0; n < 2; ++n) acc[m][n] = (f32x4){0.f, 0.f, 0.f, 0.f};

  stageA(0, 0);
  stageB(0, 0);
  asm volatile("s_waitcnt vmcnt(0)" ::: "memory");
  __builtin_amdgcn_s_barrier();

  const int arow_base = wr * 128 + lrow;
  const int brow_base = wc * 32 + lrow;
  const int aswz = lrow & 7;

  for (int t = 0; t < T; ++t) {
    const int cb = (t & 1) * 24576;
    const u16* Abuf = smem + cb;
    const u16* Bbuf = smem + cb + 16384;
    bf16x8 af[4][2], bfr[2][2];
#pragma unroll
    for (int m = 0; m < 4; ++m)
#pragma unroll
      for (int ks = 0; ks < 2; ++ks)
        af[m][ks] = *(const bf16x8*)(Abuf + (arow_base + m * 16) * 64 +
                                     (((ks * 4 + lgrp) ^ aswz) << 3));
#pragma unroll
    for (int n = 0; n < 2; ++n)
#pragma unroll
      for (int ks = 0; ks < 2; ++ks)
        bfr[n][ks] = *(const bf16x8*)(Bbuf + (brow_base + n * 16) * 64 +
                                      (((ks * 4 + lgrp) ^ aswz) << 3));
    if (t + 1 < T) stageA(t + 1, (t + 1) & 1);
    __builtin_amdgcn_s_barrier();
    __builtin_amdgcn_s_setprio(1);
#pragma unroll
    for (int m = 0; m < 4; ++m)
#pragma unroll
      for (int ks = 0; ks < 2; ++ks)
        acc[m][0] = __builtin_amdgcn_mfma_f32_16x16x32_bf16(af[m][ks], bfr[0][ks],
                                                            acc[m][0], 0, 0, 0);
    __builtin_amdgcn_s_setprio(0);
    if (t + 1 < T) stageB(t + 1, (t + 1) & 1);
    __builtin_amdgcn_s_barrier();
    __builtin_amdgcn_s_setprio(1);
#pragma unroll
    for (int m = 0; m < 4; ++m)
#pragma unroll
      for (int ks = 0; ks < 2; ++ks)
        acc[m][1] = __builtin_amdgcn_mfma_f32_16x16x32_bf16(af[m][ks], bfr[1][ks],
                                                            acc[m][1], 0, 0, 0);
    __builtin_amdgcn_s_setprio(0);
#pragma unroll
    for (int m = 0; m < 4; ++m)
#pragma unroll
      for (int ks = 0; ks < 2; ++ks)
        af[m][ks] = *(const bf16x8*)(Abuf + (arow_base + (m + 4) * 16) * 64 +
                                     (((ks * 4 + lgrp) ^ aswz) << 3));
    __builtin_amdgcn_s_barrier();
    __builtin_amdgcn_s_setprio(1);
#pragma unroll
    for (int m = 0; m < 4; ++m)
#pragma unroll
      for (int ks = 0; ks < 2; ++ks)
        acc[m + 4][0] = __builtin_amdgcn_mfma_f32_16x16x32_bf16(af[m][ks], bfr[0][ks],
                                                                acc[m + 4][0], 0, 0, 0);
    __builtin_amdgcn_s_setprio(0);
    __builtin_amdgcn_s_barrier();
    __builtin_amdgcn_s_setprio(1);
#pragma unroll
    for (int m = 0; m < 4; ++m)
#pragma unroll
      for (int ks = 0; ks < 2; ++ks)
        acc[m + 4][1] = __builtin_amdgcn_mfma_f32_16x16x32_bf16(af[m][ks], bfr[1][ks],
                                                                acc[m + 4][1], 0, 0, 0);
    __builtin_amdgcn_s_setprio(0);
    if (t + 1 < T) {
      asm volatile("s_waitcnt vmcnt(0)" ::: "memory");
      __builtin_amdgcn_s_barrier();
      __builtin_amdgcn_sched_barrier(0);
    }
  }

  u16* C = Cout + (size_t)bz * zoff;
#pragma unroll
  for (int m = 0; m < 8; ++m) {
#pragma unroll
    for (int n = 0; n < 2; ++n) {
      const int row0 = mrow + wr * 128 + m * 16 + lgrp * 4;
      const int col = ncol + wc * 32 + n * 16 + lrow;
      const float bv = (bz == 0) ? bias[col] : 0.0f;
      f32x4 v = acc[m][n];
#pragma unroll
      for (int r = 0; r < 4; r++) C[(size_t)(row0 + r) * N + col] = f2bf(v[r] + bv);
    }
  }
}

// ---------------- flash attention, KV-split=4, KVBLK=64, fixed-C softmax ----------------
__global__ __launch_bounds__(256) void k_attn_split(const u16* __restrict__ Q,
                                                    const u16* __restrict__ K,
                                                    const u16* __restrict__ Vt,
                                                    u16* __restrict__ Opart,
                                                    float* __restrict__ lpart) {
  __shared__ __align__(16) u16 Kl[2][4096];
  __shared__ __align__(16) u16 Vl[2][4096];
  const int tid = threadIdx.x, wid = tid >> 6, lane = tid & 63;
  const int ql = lane & 31, hi = lane >> 5;
  const int bx = blockIdx.x;
  const int split = bx >> 9, bh = (bx >> 4) & 31, qblk = bx & 15;
  const int qbase = qblk * 128 + wid * 32;
  const int kvS = split * 512;
  const u16* Qh = Q + (size_t)bh * SS * HD;
  const u16* Kh = K + (size_t)bh * SS * HD;
  const u16* Vh = Vt + (size_t)bh * SS * HD;

  const int lrow3 = lane >> 3;
  const int lin = lrow3 * 128 + ((((lane & 7) << 4)) ^ (lrow3 << 4));
  const int kswz = (ql & 7) << 4;

  auto stage = [&](int kv0, int bufi) {
    const char* Ks = (const char*)Kh + (size_t)kv0 * 128 + wid * 2048 + lin;
    const char* Vs = (const char*)Vh + ((size_t)(kv0 >> 6)) * 8192 + wid * 2048 + lin;
    char* kd = (char*)&Kl[bufi][0] + wid * 2048;
    char* vd = (char*)&Vl[bufi][0] + wid * 2048;
    gload_lds16(Ks, kd);
    gload_lds16(Ks + 1024, kd + 1024);
    gload_lds16(Vs, vd);
    gload_lds16(Vs + 1024, vd + 1024);
  };

  bf16x8 qf[4];
#pragma unroll
  for (int j = 0; j < 4; j++)
    qf[j] = *(const bf16x8*)&Qh[(size_t)(qbase + ql) * HD + j * 16 + hi * 8];

  f32x16 oacc0, oacc1;
#pragma unroll
  for (int r = 0; r < 16; r++) { oacc0[r] = 0.f; oacc1[r] = 0.f; }
  float lsum = 0.f;
  const float cs = 0.125f * 1.44269504f;
  const float CSHIFT = 24.0f;

  auto tileC = [&](int bufi, int tt) {
    const char* Kb = (const char*)&Kl[bufi][0];
    const char* Vb = (const char*)&Vl[bufi][0];
    bf16x8 kf[4];
#pragma unroll
    for (int j = 0; j < 4; j++)
      kf[j] = *(const bf16x8*)(Kb + (tt * 32 + ql) * 128 + ((j * 32 + hi * 16) ^ kswz));

    f32x16 s;
#pragma unroll
    for (int r = 0; r < 16; r++) s[r] = 0.f;
#pragma unroll
    for (int j = 0; j < 4; j++)
      s = __builtin_amdgcn_mfma_f32_32x32x16_bf16(kf[j], qf[j], s, 0, 0, 0);

    float p[16];
#pragma unroll
    for (int r = 0; r < 16; r++) p[r] = exp2_(fmaf(s[r], cs, -CSHIFT));
    float t0 = (p[0] + p[1]) + (p[2] + p[3]);
    float t1 = (p[4] + p[5]) + (p[6] + p[7]);
    float t2 = (p[8] + p[9]) + (p[10] + p[11]);
    float t3 = (p[12] + p[13]) + (p[14] + p[15]);
    lsum += cross32_reduce_sum((t0 + t1) + (t2 + t3));

    u32 w01 = cvt_pk_bf16(p[0], p[1]), w23 = cvt_pk_bf16(p[2], p[3]);
    u32 w45 = cvt_pk_bf16(p[4], p[5]), w67 = cvt_pk_bf16(p[6], p[7]);
    u32 w89 = cvt_pk_bf16(p[8], p[9]), wab = cvt_pk_bf16(p[10], p[11]);
    u32 wcd = cvt_pk_bf16(p[12], p[13]), wef = cvt_pk_bf16(p[14], p[15]);
    lane32_swap(w01, w45);
    lane32_swap(w23, w67);
    lane32_swap(w89, wcd);
    lane32_swap(wab, wef);
    union { u32 w[4]; bf16x8 v; } f0, f1;
    f0.w[0] = w01; f0.w[1] = w23; f0.w[2] = w45; f0.w[3] = w67;
    f1.w[0] = w89; f1.w[1] = wab; f1.w[2] = wcd; f1.w[3] = wef;

    bf16x8 vf[4];
#pragma unroll
    for (int u = 0; u < 4; u++)
      vf[u] = *(const bf16x8*)(Vb + ((u >> 1) * 32 + ql) * 128 +
                               ((tt * 64 + (u & 1) * 32 + hi * 16) ^ kswz));

    oacc0 = __builtin_amdgcn_mfma_f32_32x32x16_bf16(vf[0], f0.v, oacc0, 0, 0, 0);
    oacc0 = __builtin_amdgcn_mfma_f32_32x32x16_bf16(vf[1], f1.v, oacc0, 0, 0, 0);
    oacc1 = __builtin_amdgcn_mfma_f32_32x32x16_bf16(vf[2], f0.v, oacc1, 0, 0, 0);
    oacc1 = __builtin_amdgcn_mfma_f32_32x32x16_bf16(vf[3], f1.v, oacc1, 0, 0, 0);
  };

  stage(kvS, 0);
  __syncthreads();
  int cur = 0;
  for (int it = 0; it < 8; ++it) {
    if (it + 1 < 8) stage(kvS + (it + 1) * 64, cur ^ 1);
    tileC(cur, 0);
    tileC(cur, 1);
    __syncthreads();
    cur ^= 1;
  }

  const int rowidx = bh * SS + qbase + ql;
  u16* Orow = Opart + ((size_t)split * 32 * SS + rowidx) * HD;
  auto storeAcc = [&](const f32x16& a, int dbase) {
#pragma unroll
    for (int t = 0; t < 4; t++) {
      u64 pk = (u64)f2bf(a[4 * t]) | ((u64)f2bf(a[4 * t + 1]) << 16) |
               ((u64)f2bf(a[4 * t + 2]) << 32) | ((u64)f2bf(a[4 * t + 3]) << 48);
      *(u64*)&Orow[dbase + 4 * hi + 8 * t] = pk;
    }
  };
  storeAcc(oacc0, 0);
  storeAcc(oacc1, 32);
  if (hi == 0) lpart[(size_t)split * 32 * SS + rowidx] = lsum;
}

// ---------------- merge the 4 KV-split partials (plain sums) -> bf16 O ----------------
__global__ __launch_bounds__(256) void k_attn_merge(const u16* __restrict__ Opart,
                                                    const float* __restrict__ lpart,
                                                    u16* __restrict__ O) {
  const int g = blockIdx.x * 256 + threadIdx.x;
  const int row = g >> 4, dseg = g & 15;
  float denom = 0.f;
#pragma unroll
  for (int s = 0; s < 4; s++) denom += lpart[(size_t)s * 32 * SS + row];
  const float inv = 1.0f / denom;
  float acc[4] = {0.f, 0.f, 0.f, 0.f};
#pragma unroll
  for (int s = 0; s < 4; s++) {
    u64 pk = *(const u64*)&Opart[(((size_t)s * 32 * SS + row) * HD) + dseg * 4];
#pragma unroll
    for (int k = 0; k < 4; k++) acc[k] += bf2f((u16)(pk >> (16 * k)));
  }
  const int bh = row >> 11, s2 = row & 2047;
  const int bb = bh >> 4, h = bh & 15;
  u64 pk = (u64)f2bf(acc[0] * inv) | ((u64)f2bf(acc[1] * inv) << 16) |
           ((u64)f2bf(acc[2] * inv) << 32) | ((u64)f2bf(acc[3] * inv) << 48);
  *(u64*)&O[((size_t)(bb * SS + s2) * DM) + h * HD + dseg * 4] = pk;
}

// ---------------- fused residual(2-way) + layernorm ----------------
template <bool XBF, bool WB>
__global__ __launch_bounds__(256) void k_res_ln(const void* __restrict__ Xv,
                                                const u16* __restrict__ Y0,
                                                const u16* __restrict__ Y1,
                                                const float* __restrict__ gw,
                                                const float* __restrict__ bw,
                                                float* __restrict__ outf,
                                                u16* __restrict__ outb) {
  const int row = blockIdx.x, t = threadIdx.x;
  float x0, x1, x2, x3;
  if constexpr (XBF) {
    u64 pk = ((const u64*)Xv)[(size_t)row * 256 + t];
    x0 = bf2f((u16)pk);
    x1 = bf2f((u16)(pk >> 16));
    x2 = bf2f((u16)(pk >> 32));
    x3 = bf2f((u16)(pk >> 48));
  } else {
    float4 xv = ((const float4*)Xv)[(size_t)row * 256 + t];
    x0 = xv.x; x1 = xv.y; x2 = xv.z; x3 = xv.w;
  }
  const u64 p0 = ((const u64*)Y0)[(size_t)row * 256 + t];
  const u64 p1 = ((const u64*)Y1)[(size_t)row * 256 + t];
  float v0 = x0 + bf2f((u16)p0) + bf2f((u16)p1);
  float v1 = x1 + bf2f((u16)(p0 >> 16)) + bf2f((u16)(p1 >> 16));
  float v2 = x2 + bf2f((u16)(p0 >> 32)) + bf2f((u16)(p1 >> 32));
  float v3 = x3 + bf2f((u16)(p0 >> 48)) + bf2f((u16)(p1 >> 48));
  float s = v0 + v1 + v2 + v3;
  float s2 = v0 * v0 + v1 * v1 + v2 * v2 + v3 * v3;
#pragma unroll
  for (int off = 32; off >= 1; off >>= 1) {
    s += __shfl_down(s, off);
    s2 += __shfl_down(s2, off);
  }
  __shared__ float ps[4], ps2[4];
  const int wid = t >> 6, lane = t & 63;
  if (lane == 0) { ps[wid] = s; ps2[wid] = s2; }
  __syncthreads();
  const float ts = ps[0] + ps[1] + ps[2] + ps[3];
  const float ts2 = ps2[0] + ps2[1] + ps2[2] + ps2[3];
  const float mu = ts * (1.f / 1024.f);
  const float rs = rsqrtf(ts2 * (1.f / 1024.f) - mu * mu + 1e-5f);
  const float4 g4 = ((const float4*)gw)[t];
  const float4 b4 = ((const float4*)bw)[t];
  float o0 = (v0 - mu) * rs * g4.x + b4.x;
  float o1 = (v1 - mu) * rs * g4.y + b4.y;
  float o2 = (v2 - mu) * rs * g4.z + b4.z;
  float o3 = (v3 - mu) * rs * g4.w + b4.w;
  if constexpr (WB) {
    u64 pk = (u64)f2bf(o0) | ((u64)f2bf(o1) << 16) | ((u64)f2bf(o2) << 32) |
             ((u64)f2bf(o3) << 48);
    ((u64*)(outb + (size_t)row * DM))[t] = pk;
  } else {
    ((float4*)(outf + (size_t)row * DM))[t] = make_float4(o0, o1, o2, o3);
  }
}

extern "C" void kernel_launch(void* const* d_in, const int* in_sizes, int n_in,
                              void* d_out, int out_size, void* d_ws, size_t ws_size,
                              hipStream_t stream) {
  const float* x = (const float*)d_in[0];
  const float* Wq = (const float*)d_in[1];
  const float* bq = (const float*)d_in[2];
  const float* Wk = (const float*)d_in[3];
  const float* bk = (const float*)d_in[4];
  const float* Wv = (const float*)d_in[5];
  const float* bv = (const float*)d_in[6];
  const float* Wo = (const float*)d_in[7];
  const float* bo = (const float*)d_in[8];
  const float* g1 = (const float*)d_in[9];
  const float* b1 = (const float*)d_in[10];
  const float* g2 = (const float*)d_in[11];
  const float* b2 = (const float*)d_in[12];
  const float* W1 = (const float*)d_in[13];
  const float* bf1 = (const float*)d_in[14];
  const float* W2 = (const float*)d_in[15];
  const float* bf2 = (const float*)d_in[16];
  float* out = (float*)d_out;

  if (ws_size < 92 * MiB) return;
  char* ws = (char*)d_ws;
  u16* WqkvT = (u16*)(ws + OFF_WQKVT);
  u16* WoT = (u16*)(ws + OFF_WOT);
  u16* W1T = (u16*)(ws + OFF_W1T);
  u16* W2T = (u16*)(ws + OFF_W2T);
  u16* xb = (u16*)(ws + OFF_XB);
  u16* Qb = (u16*)(ws + OFF_QB);
  u16* Kb = (u16*)(ws + OFF_KB);
  u16* Vt = (u16*)(ws + OFF_VT);
  u16* Ob = (u16*)(ws + OFF_XB);
  u16* Opart = (u16*)(ws + OFF_OPART);
  float* lpart = (float*)(ws + OFF_ML);
  float* bqkv = (float*)(ws + OFF_BQKV);
  u16* attn0 = (u16*)(ws + OFF_ATTN0);
  u16* attn1 = (u16*)(ws + OFF_ATTN1);
  u16* hb = (u16*)(ws + OFF_HB);
  u16* f1 = (u16*)(ws + OFF_F1);
  u16* ffn0 = (u16*)(ws + OFF_FFN0);
  u16* ffn1 = (u16*)(ws + OFF_FFN1);

  // fused prep: cast + 6 transposes + bias concat in one launch
  k_prep<<<16385, 256, 0, stream>>>(x, Wq, Wk, Wv, Wo, W1, W2, bq, bk, bv, ws);

  // fused QKV projection: 256^2 tiles, grid 12x16 = 192
  k_gemm256<EPI_QKV3><<<192, 512, 0, stream>>>(xb, WqkvT, bqkv, ws, 3072, DM, 12);

  // flash attention: split=4, grid 2048, KVBLK=64
  k_attn_split<<<2048, 256, 0, stream>>>(Qb, Kb, Vt, Opart, lpart);
  k_attn_merge<<<4096, 256, 0, stream>>>(Opart, lpart, Ob);

  // Wo projection: 256x128 tiles, split-K=2, bf16 partials at ATTN0/ATTN1
  k_gemmMN<<<256, 512, 0, stream>>>(Ob, WoT, bo, attn0, DM, DM / 2, DM,
                                    (OFF_ATTN1 - OFF_ATTN0) / 2, 8, 16);
  k_res_ln<false, true><<<4096, 256, 0, stream>>>(x, attn0, attn1, g1, b1,
                                                  nullptr, hb);

  // FFN1: 256^2 tiles, grid 16x16 = 256
  k_gemm256<EPI_GELU><<<256, 512, 0, stream>>>(hb, W1T, bf1, f1, DFF, DM, 16);

  // FFN2: 256x128 tiles, split-K=2, bf16 partials at FFN0/FFN1
  k_gemmMN<<<256, 512, 0, stream>>>(f1, W2T, bf2, ffn0, DM, DFF / 2, DFF,
                                    (OFF_FFN1 - OFF_FFN0) / 2, 8, 16);
  k_res_ln<true, false><<<4096, 256, 0, stream>>>(hb, ffn0, ffn1, g2, b2, out, nullptr);
}

// Round 17
// 236.107 us; speedup vs baseline: 1.1616x; 1.0151x over previous
//
#include <hip/hip_runtime.h>
#include <cstdint>
#include <cmath>

typedef unsigned short u16;
typedef unsigned int u32;
typedef unsigned long long u64;
typedef __bf16 bf16x8 __attribute__((ext_vector_type(8)));
typedef float f32x4 __attribute__((ext_vector_type(4)));
typedef float f32x16 __attribute__((ext_vector_type(16)));
typedef int v2i __attribute__((ext_vector_type(2)));

#define AS1 __attribute__((address_space(1)))
#define AS3 __attribute__((address_space(3)))

static constexpr int DM = 1024, DFF = 4096, SS = 2048, HH = 16, HD = 64, TT = 4096;
static constexpr size_t MiB = (size_t)1 << 20;
// workspace map (bytes) — live-range audited (r15):
static constexpr size_t OFF_WQKVT = 0;
static constexpr size_t OFF_WOT = 6 * MiB;
static constexpr size_t OFF_W1T = 8 * MiB;
static constexpr size_t OFF_W2T = 16 * MiB;
static constexpr size_t OFF_XB = 24 * MiB;
static constexpr size_t OFF_QB = 32 * MiB;
static constexpr size_t OFF_KB = 40 * MiB;
static constexpr size_t OFF_VT = 48 * MiB;
static constexpr size_t OFF_OPART = 56 * MiB;
static constexpr size_t OFF_ML = 88 * MiB;
static constexpr size_t OFF_BQKV = 90 * MiB;
static constexpr size_t OFF_ATTN0 = 32 * MiB;  // bf16 partial, 8 MiB
static constexpr size_t OFF_ATTN1 = 40 * MiB;  // bf16 partial, 8 MiB
static constexpr size_t OFF_HB = 48 * MiB;     // bf16 h, 8 MiB
static constexpr size_t OFF_F1 = 56 * MiB;     // bf16 gelu out, 32 MiB
static constexpr size_t OFF_FFN0 = 24 * MiB;   // bf16 partial, 8 MiB
static constexpr size_t OFF_FFN1 = 32 * MiB;   // bf16 partial, 8 MiB

__device__ __forceinline__ u16 f2bf(float f) {
  union { float f; unsigned u; } c; c.f = f;
  unsigned r = c.u + 0x7fffu + ((c.u >> 16) & 1u);
  return (u16)(r >> 16);
}
__device__ __forceinline__ float bf2f(u16 h) {
  union { unsigned u; float f; } c; c.u = ((u32)h) << 16;
  return c.f;
}

__device__ __forceinline__ void gload_lds16(const void* g, void* l) {
  __builtin_amdgcn_global_load_lds((AS1 void*)g, (AS3 void*)l, 16, 0, 0);
}

__device__ __forceinline__ float exp2_(float x) {
#if __has_builtin(__builtin_amdgcn_exp2f)
  return __builtin_amdgcn_exp2f(x);
#else
  return exp2f(x);
#endif
}

__device__ __forceinline__ u32 cvt_pk_bf16(float lo, float hi) {
  u32 r;
  asm("v_cvt_pk_bf16_f32 %0, %1, %2" : "=v"(r) : "v"(lo), "v"(hi));
  return r;
}

__device__ __forceinline__ void lane32_swap(u32& a, u32& b) {
#if __has_builtin(__builtin_amdgcn_permlane32_swap)
  v2i r = __builtin_amdgcn_permlane32_swap((int)a, (int)b, false, false);
  a = (u32)r.x;
  b = (u32)r.y;
#else
  u32 ta = (u32)__shfl_xor((int)a, 32);
  u32 tb = (u32)__shfl_xor((int)b, 32);
  bool hi = (threadIdx.x & 32) != 0;
  u32 na = hi ? tb : a;
  u32 nb = hi ? b : ta;
  a = na;
  b = nb;
#endif
}

__device__ __forceinline__ float cross32_reduce_sum(float x) {
  u32 a = __float_as_uint(x), b = a;
  lane32_swap(a, b);
  return __uint_as_float(a) + __uint_as_float(b);
}

__device__ __forceinline__ int xcd_swizzle(int bid, int nwg) {
  int q8 = nwg >> 3;
  return (bid & 7) * q8 + (bid >> 3);
}

// ======== fused prep: cast x, transpose-cast 6 weights, concat biases ========
__global__ __launch_bounds__(256) void k_prep(const float* __restrict__ x,
                                              const float* __restrict__ Wq,
                                              const float* __restrict__ Wk,
                                              const float* __restrict__ Wv,
                                              const float* __restrict__ Wo,
                                              const float* __restrict__ W1,
                                              const float* __restrict__ W2,
                                              const float* __restrict__ bq,
                                              const float* __restrict__ bk,
                                              const float* __restrict__ bv,
                                              char* __restrict__ ws) {
  const int blk = blockIdx.x;
  const int tid = threadIdx.x;
  if (blk < 4096) {  // cast x -> xb
    u16* out = (u16*)(ws + OFF_XB);
    int i = blk * 256 + tid;
    float4 v = ((const float4*)x)[i];
    u64 pk = (u64)f2bf(v.x) | ((u64)f2bf(v.y) << 16) |
             ((u64)f2bf(v.z) << 32) | ((u64)f2bf(v.w) << 48);
    ((u64*)out)[i] = pk;
    return;
  }
  if (blk == 16384) {  // concat biases
    float* out = (float*)(ws + OFF_BQKV);
#pragma unroll
    for (int it = 0; it < 12; ++it) {
      int i = it * 256 + tid;
      out[i] = i < 1024 ? bq[i] : (i < 2048 ? bk[i - 1024] : bv[i - 2048]);
    }
    return;
  }
  const float* in;
  u16* out;
  int R, C, t;
  if (blk < 8192) {
    t = blk - 4096;
    const int w = t >> 10;
    t &= 1023;
    R = DM; C = DM;
    if (w == 0) { in = Wq; out = (u16*)(ws + OFF_WQKVT); }
    else if (w == 1) { in = Wk; out = (u16*)(ws + OFF_WQKVT) + 1024 * 1024; }
    else if (w == 2) { in = Wv; out = (u16*)(ws + OFF_WQKVT) + 2048 * 1024; }
    else { in = Wo; out = (u16*)(ws + OFF_WOT); }
  } else if (blk < 12288) {
    t = blk - 8192;
    R = DM; C = DFF;
    in = W1; out = (u16*)(ws + OFF_W1T);
  } else {
    t = blk - 12288;
    R = DFF; C = DM;
    in = W2; out = (u16*)(ws + OFF_W2T);
  }
  const int ntx = C >> 5;
  const int cb = (t % ntx) * 32, rb = (t / ntx) * 32;
  __shared__ u16 tile[32][33];
  const int tx = tid & 31;
  const int ty = tid >> 5;
#pragma unroll
  for (int i = 0; i < 4; i++) {
    int r = ty + i * 8;
    tile[r][tx] = f2bf(in[(size_t)(rb + r) * C + cb + tx]);
  }
  __syncthreads();
#pragma unroll
  for (int i = 0; i < 4; i++) {
    int r2 = ty + i * 8;
    out[(size_t)(cb + r2) * R + rb + tx] = tile[tx][r2];
  }
}

enum { EPI_F32 = 0, EPI_GELU = 1 };

// ======== 256x192 8-wave BK=64 QKV GEMM: grid 16x16=256 (1 block per CU) ========
// Per-wave 128x48 (acc[8][3]); LDS 112 KiB = 2 x (A 32KB + B 24KB). Same drain
// schedule / swizzle as k_gemm256; epilogue scatters Q/K/V^T.
__global__ __launch_bounds__(512) void k_gemmQKV(const u16* __restrict__ A,
                                                 const u16* __restrict__ Bt,
                                                 const float* __restrict__ bias,
                                                 char* __restrict__ wsb, int K) {
  __shared__ __align__(16) u16 smem[57344];  // 112 KiB
  const int tid = threadIdx.x;
  const int wid = tid >> 6, lane = tid & 63;
  const int lrow = lane & 15, lgrp = lane >> 4;
  const int wr = wid >> 2, wc = wid & 3;  // wave grid 2M x 4N (128x48 each)
  const int swz = xcd_swizzle(blockIdx.x, gridDim.x);
  const int mrow = (swz >> 4) * 256, ncol = (swz & 15) * 192;

  const int srow = tid >> 3;
  const int sgd = tid & 7;
  const int gsw = (sgd ^ (srow & 7)) << 3;
  const u16* aS0 = A + (size_t)(mrow + srow) * K + gsw;
  const u16* bS0 = Bt + (size_t)(ncol + srow) * K + gsw;
  const int T = K >> 6;

  auto stageA = [&](int t, int b) {
    u16* dst = smem + b * 28672 + wid * 512;
    const u16* s = aS0 + t * 64;
#pragma unroll
    for (int c = 0; c < 4; ++c) gload_lds16(s + (size_t)c * 64 * K, dst + c * 4096);
  };
  auto stageB = [&](int t, int b) {
    u16* dst = smem + b * 28672 + 16384 + wid * 512;
    const u16* s = bS0 + t * 64;
#pragma unroll
    for (int c = 0; c < 3; ++c) gload_lds16(s + (size_t)c * 64 * K, dst + c * 4096);
  };

  f32x4 acc[8][3];
#pragma unroll
  for (int m = 0; m < 8; ++m)
#pragma unroll
    for (int n = 0; n < 3; ++n) acc[m][n] = (f32x4){0.f, 0.f, 0.f, 0.f};

  stageA(0, 0);
  stageB(0, 0);
  asm volatile("s_waitcnt vmcnt(0)" ::: "memory");
  __builtin_amdgcn_s_barrier();

  const int arow_base = wr * 128 + lrow;
  const int brow_base = wc * 48 + lrow;
  const int aswz = lrow & 7;

  for (int t = 0; t < T; ++t) {
    const u16* Abuf = smem + (t & 1) * 28672;
    const u16* Bbuf = smem + (t & 1) * 28672 + 16384;
    bf16x8 af[4][2], bfr[3][2];
    // phase 0: read A m0-3 + all B (n0-2); stage A next; MFMA m0-3 x n0-1
#pragma unroll
    for (int m = 0; m < 4; ++m)
#pragma unroll
      for (int ks = 0; ks < 2; ++ks)
        af[m][ks] = *(const bf16x8*)(Abuf + (arow_base + m * 16) * 64 +
                                     (((ks * 4 + lgrp) ^ aswz) << 3));
#pragma unroll
    for (int n = 0; n < 3; ++n)
#pragma unroll
      for (int ks = 0; ks < 2; ++ks)
        bfr[n][ks] = *(const bf16x8*)(Bbuf + (brow_base + n * 16) * 64 +
                                      (((ks * 4 + lgrp) ^ aswz) << 3));
    if (t + 1 < T) stageA(t + 1, (t + 1) & 1);
    __builtin_amdgcn_s_barrier();
    __builtin_amdgcn_s_setprio(1);
#pragma unroll
    for (int m = 0; m < 4; ++m)
#pragma unroll
      for (int n = 0; n < 2; ++n)
#pragma unroll
        for (int ks = 0; ks < 2; ++ks)
          acc[m][n] = __builtin_amdgcn_mfma_f32_16x16x32_bf16(af[m][ks], bfr[n][ks],
                                                              acc[m][n], 0, 0, 0);
    __builtin_amdgcn_s_setprio(0);
    // phase 1: stage B next; MFMA m0-3 x n2
    if (t + 1 < T) stageB(t + 1, (t + 1) & 1);
    __builtin_amdgcn_s_barrier();
    __builtin_amdgcn_s_setprio(1);
#pragma unroll
    for (int m = 0; m < 4; ++m)
#pragma unroll
      for (int ks = 0; ks < 2; ++ks)
        acc[m][2] = __builtin_amdgcn_mfma_f32_16x16x32_bf16(af[m][ks], bfr[2][ks],
                                                            acc[m][2], 0, 0, 0);
    __builtin_amdgcn_s_setprio(0);
    // phase 2: read A m4-7; MFMA m4-7 x n0-1
#pragma unroll
    for (int m = 0; m < 4; ++m)
#pragma unroll
      for (int ks = 0; ks < 2; ++ks)
        af[m][ks] = *(const bf16x8*)(Abuf + (arow_base + (m + 4) * 16) * 64 +
                                     (((ks * 4 + lgrp) ^ aswz) << 3));
    __builtin_amdgcn_s_barrier();
    __builtin_amdgcn_s_setprio(1);
#pragma unroll
    for (int m = 0; m < 4; ++m)
#pragma unroll
      for (int n = 0; n < 2; ++n)
#pragma unroll
        for (int ks = 0; ks < 2; ++ks)
          acc[m + 4][n] = __builtin_amdgcn_mfma_f32_16x16x32_bf16(af[m][ks], bfr[n][ks],
                                                                  acc[m + 4][n], 0, 0, 0);
    __builtin_amdgcn_s_setprio(0);
    // phase 3: MFMA m4-7 x n2
    __builtin_amdgcn_s_barrier();
    __builtin_amdgcn_s_setprio(1);
#pragma unroll
    for (int m = 0; m < 4; ++m)
#pragma unroll
      for (int ks = 0; ks < 2; ++ks)
        acc[m + 4][2] = __builtin_amdgcn_mfma_f32_16x16x32_bf16(af[m][ks], bfr[2][ks],
                                                                acc[m + 4][2], 0, 0, 0);
    __builtin_amdgcn_s_setprio(0);
    if (t + 1 < T) {
      asm volatile("s_waitcnt vmcnt(0)" ::: "memory");
      __builtin_amdgcn_s_barrier();
      __builtin_amdgcn_sched_barrier(0);
    }
  }

#pragma unroll
  for (int m = 0; m < 8; ++m) {
#pragma unroll
    for (int n = 0; n < 3; ++n) {
      const int row0 = mrow + wr * 128 + m * 16 + lgrp * 4;
      const int col = ncol + wc * 48 + n * 16 + lrow;
      const float bv = bias[col];
      f32x4 v = acc[m][n];
      const int seg = col >> 10, cc = col & 1023;
      const int h = cc >> 6, d = cc & 63;
      if (seg < 2) {
        u16* dst = (u16*)(wsb + (seg == 0 ? OFF_QB : OFF_KB));
#pragma unroll
        for (int r = 0; r < 4; r++) {
          const int row = row0 + r;
          const int b = row >> 11, s = row & 2047;
          dst[((size_t)(b * HH + h) * SS + s) * HD + d] = f2bf(v[r] + bv);
        }
      } else {
        u16* Vt = (u16*)(wsb + OFF_VT);
        const int b = row0 >> 11, s = row0 & 2047;
        u64 pk = (u64)f2bf(v[0] + bv) | ((u64)f2bf(v[1] + bv) << 16) |
                 ((u64)f2bf(v[2] + bv) << 32) | ((u64)f2bf(v[3] + bv) << 48);
        size_t addr = ((size_t)(b * HH + h) * (SS / 64) + (s >> 6)) * 4096 +
                      (size_t)d * 64 + (s & 63);
        *(u64*)&Vt[addr] = pk;
      }
    }
  }
}

// ======== 256x256 8-wave BK=64 deep-pipelined GEMM (full K), XCD-swizzled ========
template <int EPI>
__global__ __launch_bounds__(512) void k_gemm256(const u16* __restrict__ A,
                                                 const u16* __restrict__ Bt,
                                                 const float* __restrict__ bias,
                                                 void* __restrict__ Cout,
                                                 int N, int K, int nx) {
  __shared__ __align__(16) u16 smem[65536];  // 128 KiB
  const int tid = threadIdx.x;
  const int wid = tid >> 6, lane = tid & 63;
  const int lrow = lane & 15, lgrp = lane >> 4;
  const int wr = wid >> 2, wc = wid & 3;
  const int swz = xcd_swizzle(blockIdx.x, gridDim.x);
  const int mrow = (swz / nx) * 256, ncol = (swz % nx) * 256;

  const int srow = tid >> 3;
  const int sgd = tid & 7;
  const int gsw = (sgd ^ (srow & 7)) << 3;
  const u16* aS0 = A + (size_t)(mrow + srow) * K + gsw;
  const u16* bS0 = Bt + (size_t)(ncol + srow) * K + gsw;
  const int T = K >> 6;

  auto stageA = [&](int t, int b) {
    u16* dst = smem + b * 32768 + wid * 512;
    const u16* s = aS0 + t * 64;
#pragma unroll
    for (int c = 0; c < 4; ++c) gload_lds16(s + (size_t)c * 64 * K, dst + c * 4096);
  };
  auto stageB = [&](int t, int b) {
    u16* dst = smem + b * 32768 + 16384 + wid * 512;
    const u16* s = bS0 + t * 64;
#pragma unroll
    for (int c = 0; c < 4; ++c) gload_lds16(s + (size_t)c * 64 * K, dst + c * 4096);
  };

  f32x4 acc[8][4];
#pragma unroll
  for (int m = 0; m < 8; ++m)
#pragma unroll
    for (int n = 0; n < 4; ++n) acc[m][n] = (f32x4){0.f, 0.f, 0.f, 0.f};

  stageA(0, 0);
  stageB(0, 0);
  asm volatile("s_waitcnt vmcnt(0)" ::: "memory");
  __builtin_amdgcn_s_barrier();

  const int arow_base = wr * 128 + lrow;
  const int brow_base = wc * 64 + lrow;
  const int aswz = lrow & 7;

  for (int t = 0; t < T; ++t) {
    const int cb = (t & 1) * 32768;
    const u16* Abuf = smem + cb;
    const u16* Bbuf = smem + cb + 16384;
    bf16x8 af[4][2], bfr[4][2];
#pragma unroll
    for (int m = 0; m < 4; ++m)
#pragma unroll
      for (int ks = 0; ks < 2; ++ks)
        af[m][ks] = *(const bf16x8*)(Abuf + (arow_base + m * 16) * 64 +
                                     (((ks * 4 + lgrp) ^ aswz) << 3));
#pragma unroll
    for (int n = 0; n < 4; ++n)
#pragma unroll
      for (int ks = 0; ks < 2; ++ks)
        bfr[n][ks] = *(const bf16x8*)(Bbuf + (brow_base + n * 16) * 64 +
                                      (((ks * 4 + lgrp) ^ aswz) << 3));
    if (t + 1 < T) stageA(t + 1, (t + 1) & 1);
    __builtin_amdgcn_s_barrier();
    __builtin_amdgcn_s_setprio(1);
#pragma unroll
    for (int m = 0; m < 4; ++m)
#pragma unroll
      for (int n = 0; n < 2; ++n)
#pragma unroll
        for (int ks = 0; ks < 2; ++ks)
          acc[m][n] = __builtin_amdgcn_mfma_f32_16x16x32_bf16(af[m][ks], bfr[n][ks],
                                                              acc[m][n], 0, 0, 0);
    __builtin_amdgcn_s_setprio(0);
    if (t + 1 < T) stageB(t + 1, (t + 1) & 1);
    __builtin_amdgcn_s_barrier();
    __builtin_amdgcn_s_setprio(1);
#pragma unroll
    for (int m = 0; m < 4; ++m)
#pragma unroll
      for (int n = 2; n < 4; ++n)
#pragma unroll
        for (int ks = 0; ks < 2; ++ks)
          acc[m][n] = __builtin_amdgcn_mfma_f32_16x16x32_bf16(af[m][ks], bfr[n][ks],
                                                              acc[m][n], 0, 0, 0);
    __builtin_amdgcn_s_setprio(0);
#pragma unroll
    for (int m = 0; m < 4; ++m)
#pragma unroll
      for (int ks = 0; ks < 2; ++ks)
        af[m][ks] = *(const bf16x8*)(Abuf + (arow_base + (m + 4) * 16) * 64 +
                                     (((ks * 4 + lgrp) ^ aswz) << 3));
    __builtin_amdgcn_s_barrier();
    __builtin_amdgcn_s_setprio(1);
#pragma unroll
    for (int m = 0; m < 4; ++m)
#pragma unroll
      for (int n = 0; n < 2; ++n)
#pragma unroll
        for (int ks = 0; ks < 2; ++ks)
          acc[m + 4][n] = __builtin_amdgcn_mfma_f32_16x16x32_bf16(af[m][ks], bfr[n][ks],
                                                                  acc[m + 4][n], 0, 0, 0);
    __builtin_amdgcn_s_setprio(0);
    __builtin_amdgcn_s_barrier();
    __builtin_amdgcn_s_setprio(1);
#pragma unroll
    for (int m = 0; m < 4; ++m)
#pragma unroll
      for (int n = 2; n < 4; ++n)
#pragma unroll
        for (int ks = 0; ks < 2; ++ks)
          acc[m + 4][n] = __builtin_amdgcn_mfma_f32_16x16x32_bf16(af[m][ks], bfr[n][ks],
                                                                  acc[m + 4][n], 0, 0, 0);
    __builtin_amdgcn_s_setprio(0);
    if (t + 1 < T) {
      asm volatile("s_waitcnt vmcnt(0)" ::: "memory");
      __builtin_amdgcn_s_barrier();
      __builtin_amdgcn_sched_barrier(0);
    }
  }

#pragma unroll
  for (int m = 0; m < 8; ++m) {
#pragma unroll
    for (int n = 0; n < 4; ++n) {
      const int row0 = mrow + wr * 128 + m * 16 + lgrp * 4;
      const int col = ncol + wc * 64 + n * 16 + lrow;
      f32x4 v = acc[m][n];
      if constexpr (EPI == EPI_GELU) {
        const float bv = bias[col];
        u16* C = (u16*)Cout;
#pragma unroll
        for (int r = 0; r < 4; r++) {
          float xg = v[r] + bv;
          float gl = 0.5f * xg * (1.0f + erff(xg * 0.70710678118654752f));
          C[(size_t)(row0 + r) * N + col] = f2bf(gl);
        }
      } else {
        const float bv = bias[col];
        float* C = (float*)Cout;
#pragma unroll
        for (int r = 0; r < 4; r++) C[(size_t)(row0 + r) * N + col] = v[r] + bv;
      }
    }
  }
}

// ======== 256x128 8-wave BK=64 GEMM, split-K, bf16 partial output ========
__global__ __launch_bounds__(512) void k_gemmMN(const u16* __restrict__ A,
                                                const u16* __restrict__ Bt,
                                                const float* __restrict__ bias,
                                                u16* __restrict__ Cout,
                                                int N, int Ksub, int stride,
                                                size_t zoff, int nx, int ny) {
  __shared__ __align__(16) u16 smem[49152];  // 96 KiB
  const int tid = threadIdx.x;
  const int wid = tid >> 6, lane = tid & 63;
  const int lrow = lane & 15, lgrp = lane >> 4;
  const int wr = wid >> 2, wc = wid & 3;
  const int swz = xcd_swizzle(blockIdx.x, gridDim.x);
  const int bx = swz % nx;
  const int by = (swz / nx) % ny;
  const int bz = swz / (nx * ny);
  const int mrow = by * 256, ncol = bx * 128;

  const int srow = tid >> 3;
  const int sgd = tid & 7;
  const int gsw = (sgd ^ (srow & 7)) << 3;
  const u16* aS0 = A + (size_t)(mrow + srow) * stride + (size_t)bz * Ksub + gsw;
  const u16* bS0 = Bt + (size_t)(ncol + srow) * stride + (size_t)bz * Ksub + gsw;
  const int T = Ksub >> 6;

  auto stageA = [&](int t, int b) {
    u16* dst = smem + b * 24576 + wid * 512;
    const u16* s = aS0 + t * 64;
#pragma unroll
    for (int c = 0; c < 4; ++c) gload_lds16(s + (size_t)c * 64 * stride, dst + c * 4096);
  };
  auto stageB = [&](int t, int b) {
    u16* dst = smem + b * 24576 + 16384 + wid * 512;
    const u16* s = bS0 + t * 64;
#pragma unroll
    for (int c = 0; c < 2; ++c) gload_lds16(s + (size_t)c * 64 * stride, dst + c * 4096);
  };

  f32x4 acc[8][2];
#pragma unroll
  for (int m = 0; m < 8; ++m)
#pragma unroll
    for (int n = 0; n < 2; ++n) acc[m][n] = (f32x4){0.f, 0.f, 0.f, 0.f};

  stageA(0, 0);
  stageB(0, 0);
  asm volatile("s_waitcnt vmcnt(0)" ::: "memory");
  __builtin_amdgcn_s_barrier();

  const int arow_base = wr * 128 + lrow;
  const int brow_base = wc * 32 + lrow;
  const int aswz = lrow & 7;

  for (int t = 0; t < T; ++t) {
    const int cb = (t & 1) * 24576;
    const u16* Abuf = smem + cb;
    const u16* Bbuf = smem + cb + 16384;
    bf16x8 af[4][2], bfr[2][2];
#pragma unroll
    for (int m = 0; m < 4; ++m)
#pragma unroll
      for (int ks = 0; ks < 2; ++ks)
        af[m][ks] = *(const bf16x8*)(Abuf + (arow_base + m * 16) * 64 +
                                     (((ks * 4 + lgrp) ^ aswz) << 3));
#pragma unroll
    for (int n = 0; n < 2; ++n)
#pragma unroll
      for (int ks = 0; ks < 2; ++ks)
        bfr[n][ks] = *(const bf16x8*)(Bbuf + (brow_base + n * 16) * 64 +
                                      (((ks * 4 + lgrp) ^ aswz) << 3));
    if (t + 1 < T) stageA(t + 1, (t + 1) & 1);
    __builtin_amdgcn_s_barrier();
    __builtin_amdgcn_s_setprio(1);
#pragma unroll
    for (int m = 0; m < 4; ++m)
#pragma unroll
      for (int ks = 0; ks < 2; ++ks)
        acc[m][0] = __builtin_amdgcn_mfma_f32_16x16x32_bf16(af[m][ks], bfr[0][ks],
                                                            acc[m][0], 0, 0, 0);
    __builtin_amdgcn_s_setprio(0);
    if (t + 1 < T) stageB(t + 1, (t + 1) & 1);
    __builtin_amdgcn_s_barrier();
    __builtin_amdgcn_s_setprio(1);
#pragma unroll
    for (int m = 0; m < 4; ++m)
#pragma unroll
      for (int ks = 0; ks < 2; ++ks)
        acc[m][1] = __builtin_amdgcn_mfma_f32_16x16x32_bf16(af[m][ks], bfr[1][ks],
                                                            acc[m][1], 0, 0, 0);
    __builtin_amdgcn_s_setprio(0);
#pragma unroll
    for (int m = 0; m < 4; ++m)
#pragma unroll
      for (int ks = 0; ks < 2; ++ks)
        af[m][ks] = *(const bf16x8*)(Abuf + (arow_base + (m + 4) * 16) * 64 +
                                     (((ks * 4 + lgrp) ^ aswz) << 3));
    __builtin_amdgcn_s_barrier();
    __builtin_amdgcn_s_setprio(1);
#pragma unroll
    for (int m = 0; m < 4; ++m)
#pragma unroll
      for (int ks = 0; ks < 2; ++ks)
        acc[m + 4][0] = __builtin_amdgcn_mfma_f32_16x16x32_bf16(af[m][ks], bfr[0][ks],
                                                                acc[m + 4][0], 0, 0, 0);
    __builtin_amdgcn_s_setprio(0);
    __builtin_amdgcn_s_barrier();
    __builtin_amdgcn_s_setprio(1);
#pragma unroll
    for (int m = 0; m < 4; ++m)
#pragma unroll
      for (int ks = 0; ks < 2; ++ks)
        acc[m + 4][1] = __builtin_amdgcn_mfma_f32_16x16x32_bf16(af[m][ks], bfr[1][ks],
                                                                acc[m + 4][1], 0, 0, 0);
    __builtin_amdgcn_s_setprio(0);
    if (t + 1 < T) {
      asm volatile("s_waitcnt vmcnt(0)" ::: "memory");
      __builtin_amdgcn_s_barrier();
      __builtin_amdgcn_sched_barrier(0);
    }
  }

  u16* C = Cout + (size_t)bz * zoff;
#pragma unroll
  for (int m = 0; m < 8; ++m) {
#pragma unroll
    for (int n = 0; n < 2; ++n) {
      const int row0 = mrow + wr * 128 + m * 16 + lgrp * 4;
      const int col = ncol + wc * 32 + n * 16 + lrow;
      const float bv = (bz == 0) ? bias[col] : 0.0f;
      f32x4 v = acc[m][n];
#pragma unroll
      for (int r = 0; r < 4; r++) C[(size_t)(row0 + r) * N + col] = f2bf(v[r] + bv);
    }
  }
}

// ---------------- flash attention, KV-split=4, KVBLK=64, fixed-C softmax ----------------
__global__ __launch_bounds__(256) void k_attn_split(const u16* __restrict__ Q,
                                                    const u16* __restrict__ K,
                                                    const u16* __restrict__ Vt,
                                                    u16* __restrict__ Opart,
                                                    float* __restrict__ lpart) {
  __shared__ __align__(16) u16 Kl[2][4096];
  __shared__ __align__(16) u16 Vl[2][4096];
  const int tid = threadIdx.x, wid = tid >> 6, lane = tid & 63;
  const int ql = lane & 31, hi = lane >> 5;
  const int bx = blockIdx.x;
  const int split = bx >> 9, bh = (bx >> 4) & 31, qblk = bx & 15;
  const int qbase = qblk * 128 + wid * 32;
  const int kvS = split * 512;
  const u16* Qh = Q + (size_t)bh * SS * HD;
  const u16* Kh = K + (size_t)bh * SS * HD;
  const u16* Vh = Vt + (size_t)bh * SS * HD;

  const int lrow3 = lane >> 3;
  const int lin = lrow3 * 128 + ((((lane & 7) << 4)) ^ (lrow3 << 4));
  const int kswz = (ql & 7) << 4;

  auto stage = [&](int kv0, int bufi) {
    const char* Ks = (const char*)Kh + (size_t)kv0 * 128 + wid * 2048 + lin;
    const char* Vs = (const char*)Vh + ((size_t)(kv0 >> 6)) * 8192 + wid * 2048 + lin;
    char* kd = (char*)&Kl[bufi][0] + wid * 2048;
    char* vd = (char*)&Vl[bufi][0] + wid * 2048;
    gload_lds16(Ks, kd);
    gload_lds16(Ks + 1024, kd + 1024);
    gload_lds16(Vs, vd);
    gload_lds16(Vs + 1024, vd + 1024);
  };

  bf16x8 qf[4];
#pragma unroll
  for (int j = 0; j < 4; j++)
    qf[j] = *(const bf16x8*)&Qh[(size_t)(qbase + ql) * HD + j * 16 + hi * 8];

  f32x16 oacc0, oacc1;
#pragma unroll
  for (int r = 0; r < 16; r++) { oacc0[r] = 0.f; oacc1[r] = 0.f; }
  float lsum = 0.f;
  const float cs = 0.125f * 1.44269504f;
  const float CSHIFT = 24.0f;

  auto tileC = [&](int bufi, int tt) {
    const char* Kb = (const char*)&Kl[bufi][0];
    const char* Vb = (const char*)&Vl[bufi][0];
    bf16x8 kf[4];
#pragma unroll
    for (int j = 0; j < 4; j++)
      kf[j] = *(const bf16x8*)(Kb + (tt * 32 + ql) * 128 + ((j * 32 + hi * 16) ^ kswz));

    f32x16 s;
#pragma unroll
    for (int r = 0; r < 16; r++) s[r] = 0.f;
#pragma unroll
    for (int j = 0; j < 4; j++)
      s = __builtin_amdgcn_mfma_f32_32x32x16_bf16(kf[j], qf[j], s, 0, 0, 0);

    float p[16];
#pragma unroll
    for (int r = 0; r < 16; r++) p[r] = exp2_(fmaf(s[r], cs, -CSHIFT));
    float t0 = (p[0] + p[1]) + (p[2] + p[3]);
    float t1 = (p[4] + p[5]) + (p[6] + p[7]);
    float t2 = (p[8] + p[9]) + (p[10] + p[11]);
    float t3 = (p[12] + p[13]) + (p[14] + p[15]);
    lsum += cross32_reduce_sum((t0 + t1) + (t2 + t3));

    u32 w01 = cvt_pk_bf16(p[0], p[1]), w23 = cvt_pk_bf16(p[2], p[3]);
    u32 w45 = cvt_pk_bf16(p[4], p[5]), w67 = cvt_pk_bf16(p[6], p[7]);
    u32 w89 = cvt_pk_bf16(p[8], p[9]), wab = cvt_pk_bf16(p[10], p[11]);
    u32 wcd = cvt_pk_bf16(p[12], p[13]), wef = cvt_pk_bf16(p[14], p[15]);
    lane32_swap(w01, w45);
    lane32_swap(w23, w67);
    lane32_swap(w89, wcd);
    lane32_swap(wab, wef);
    union { u32 w[4]; bf16x8 v; } f0, f1;
    f0.w[0] = w01; f0.w[1] = w23; f0.w[2] = w45; f0.w[3] = w67;
    f1.w[0] = w89; f1.w[1] = wab; f1.w[2] = wcd; f1.w[3] = wef;

    bf16x8 vf[4];
#pragma unroll
    for (int u = 0; u < 4; u++)
      vf[u] = *(const bf16x8*)(Vb + ((u >> 1) * 32 + ql) * 128 +
                               ((tt * 64 + (u & 1) * 32 + hi * 16) ^ kswz));

    oacc0 = __builtin_amdgcn_mfma_f32_32x32x16_bf16(vf[0], f0.v, oacc0, 0, 0, 0);
    oacc0 = __builtin_amdgcn_mfma_f32_32x32x16_bf16(vf[1], f1.v, oacc0, 0, 0, 0);
    oacc1 = __builtin_amdgcn_mfma_f32_32x32x16_bf16(vf[2], f0.v, oacc1, 0, 0, 0);
    oacc1 = __builtin_amdgcn_mfma_f32_32x32x16_bf16(vf[3], f1.v, oacc1, 0, 0, 0);
  };

  stage(kvS, 0);
  __syncthreads();
  int cur = 0;
  for (int it = 0; it < 8; ++it) {
    if (it + 1 < 8) stage(kvS + (it + 1) * 64, cur ^ 1);
    tileC(cur, 0);
    tileC(cur, 1);
    __syncthreads();
    cur ^= 1;
  }

  const int rowidx = bh * SS + qbase + ql;
  u16* Orow = Opart + ((size_t)split * 32 * SS + rowidx) * HD;
  auto storeAcc = [&](const f32x16& a, int dbase) {
#pragma unroll
    for (int t = 0; t < 4; t++) {
      u64 pk = (u64)f2bf(a[4 * t]) | ((u64)f2bf(a[4 * t + 1]) << 16) |
               ((u64)f2bf(a[4 * t + 2]) << 32) | ((u64)f2bf(a[4 * t + 3]) << 48);
      *(u64*)&Orow[dbase + 4 * hi + 8 * t] = pk;
    }
  };
  storeAcc(oacc0, 0);
  storeAcc(oacc1, 32);
  if (hi == 0) lpart[(size_t)split * 32 * SS + rowidx] = lsum;
}

// ---------------- merge the 4 KV-split partials (plain sums) -> bf16 O ----------------
__global__ __launch_bounds__(256) void k_attn_merge(const u16* __restrict__ Opart,
                                                    const float* __restrict__ lpart,
                                                    u16* __restrict__ O) {
  const int g = blockIdx.x * 256 + threadIdx.x;
  const int row = g >> 4, dseg = g & 15;
  float denom = 0.f;
#pragma unroll
  for (int s = 0; s < 4; s++) denom += lpart[(size_t)s * 32 * SS + row];
  const float inv = 1.0f / denom;
  float acc[4] = {0.f, 0.f, 0.f, 0.f};
#pragma unroll
  for (int s = 0; s < 4; s++) {
    u64 pk = *(const u64*)&Opart[(((size_t)s * 32 * SS + row) * HD) + dseg * 4];
#pragma unroll
    for (int k = 0; k < 4; k++) acc[k] += bf2f((u16)(pk >> (16 * k)));
  }
  const int bh = row >> 11, s2 = row & 2047;
  const int bb = bh >> 4, h = bh & 15;
  u64 pk = (u64)f2bf(acc[0] * inv) | ((u64)f2bf(acc[1] * inv) << 16) |
           ((u64)f2bf(acc[2] * inv) << 32) | ((u64)f2bf(acc[3] * inv) << 48);
  *(u64*)&O[((size_t)(bb * SS + s2) * DM) + h * HD + dseg * 4] = pk;
}

// ---------------- fused residual(2-way) + layernorm ----------------
template <bool XBF, bool WB>
__global__ __launch_bounds__(256) void k_res_ln(const void* __restrict__ Xv,
                                                const u16* __restrict__ Y0,
                                                const u16* __restrict__ Y1,
                                                const float* __restrict__ gw,
                                                const float* __restrict__ bw,
                                                float* __restrict__ outf,
                                                u16* __restrict__ outb) {
  const int row = blockIdx.x, t = threadIdx.x;
  float x0, x1, x2, x3;
  if constexpr (XBF) {
    u64 pk = ((const u64*)Xv)[(size_t)row * 256 + t];
    x0 = bf2f((u16)pk);
    x1 = bf2f((u16)(pk >> 16));
    x2 = bf2f((u16)(pk >> 32));
    x3 = bf2f((u16)(pk >> 48));
  } else {
    float4 xv = ((const float4*)Xv)[(size_t)row * 256 + t];
    x0 = xv.x; x1 = xv.y; x2 = xv.z; x3 = xv.w;
  }
  const u64 p0 = ((const u64*)Y0)[(size_t)row * 256 + t];
  const u64 p1 = ((const u64*)Y1)[(size_t)row * 256 + t];
  float v0 = x0 + bf2f((u16)p0) + bf2f((u16)p1);
  float v1 = x1 + bf2f((u16)(p0 >> 16)) + bf2f((u16)(p1 >> 16));
  float v2 = x2 + bf2f((u16)(p0 >> 32)) + bf2f((u16)(p1 >> 32));
  float v3 = x3 + bf2f((u16)(p0 >> 48)) + bf2f((u16)(p1 >> 48));
  float s = v0 + v1 + v2 + v3;
  float s2 = v0 * v0 + v1 * v1 + v2 * v2 + v3 * v3;
#pragma unroll
  for (int off = 32; off >= 1; off >>= 1) {
    s += __shfl_down(s, off);
    s2 += __shfl_down(s2, off);
  }
  __shared__ float ps[4], ps2[4];
  const int wid = t >> 6, lane = t & 63;
  if (lane == 0) { ps[wid] = s; ps2[wid] = s2; }
  __syncthreads();
  const float ts = ps[0] + ps[1] + ps[2] + ps[3];
  const float ts2 = ps2[0] + ps2[1] + ps2[2] + ps2[3];
  const float mu = ts * (1.f / 1024.f);
  const float rs = rsqrtf(ts2 * (1.f / 1024.f) - mu * mu + 1e-5f);
  const float4 g4 = ((const float4*)gw)[t];
  const float4 b4 = ((const float4*)bw)[t];
  float o0 = (v0 - mu) * rs * g4.x + b4.x;
  float o1 = (v1 - mu) * rs * g4.y + b4.y;
  float o2 = (v2 - mu) * rs * g4.z + b4.z;
  float o3 = (v3 - mu) * rs * g4.w + b4.w;
  if constexpr (WB) {
    u64 pk = (u64)f2bf(o0) | ((u64)f2bf(o1) << 16) | ((u64)f2bf(o2) << 32) |
             ((u64)f2bf(o3) << 48);
    ((u64*)(outb + (size_t)row * DM))[t] = pk;
  } else {
    ((float4*)(outf + (size_t)row * DM))[t] = make_float4(o0, o1, o2, o3);
  }
}

extern "C" void kernel_launch(void* const* d_in, const int* in_sizes, int n_in,
                              void* d_out, int out_size, void* d_ws, size_t ws_size,
                              hipStream_t stream) {
  const float* x = (const float*)d_in[0];
  const float* Wq = (const float*)d_in[1];
  const float* bq = (const float*)d_in[2];
  const float* Wk = (const float*)d_in[3];
  const float* bk = (const float*)d_in[4];
  const float* Wv = (const float*)d_in[5];
  const float* bv = (const float*)d_in[6];
  const float* Wo = (const float*)d_in[7];
  const float* bo = (const float*)d_in[8];
  const float* g1 = (const float*)d_in[9];
  const float* b1 = (const float*)d_in[10];
  const float* g2 = (const float*)d_in[11];
  const float* b2 = (const float*)d_in[12];
  const float* W1 = (const float*)d_in[13];
  const float* bf1 = (const float*)d_in[14];
  const float* W2 = (const float*)d_in[15];
  const float* bf2 = (const float*)d_in[16];
  float* out = (float*)d_out;

  if (ws_size < 92 * MiB) return;
  char* ws = (char*)d_ws;
  u16* WqkvT = (u16*)(ws + OFF_WQKVT);
  u16* WoT = (u16*)(ws + OFF_WOT);
  u16* W1T = (u16*)(ws + OFF_W1T);
  u16* W2T = (u16*)(ws + OFF_W2T);
  u16* xb = (u16*)(ws + OFF_XB);
  u16* Qb = (u16*)(ws + OFF_QB);
  u16* Kb = (u16*)(ws + OFF_KB);
  u16* Vt = (u16*)(ws + OFF_VT);
  u16* Ob = (u16*)(ws + OFF_XB);
  u16* Opart = (u16*)(ws + OFF_OPART);
  float* lpart = (float*)(ws + OFF_ML);
  float* bqkv = (float*)(ws + OFF_BQKV);
  u16* attn0 = (u16*)(ws + OFF_ATTN0);
  u16* attn1 = (u16*)(ws + OFF_ATTN1);
  u16* hb = (u16*)(ws + OFF_HB);
  u16* f1 = (u16*)(ws + OFF_F1);
  u16* ffn0 = (u16*)(ws + OFF_FFN0);
  u16* ffn1 = (u16*)(ws + OFF_FFN1);

  // fused prep: cast + 6 transposes + bias concat in one launch
  k_prep<<<16385, 256, 0, stream>>>(x, Wq, Wk, Wv, Wo, W1, W2, bq, bk, bv, ws);

  // fused QKV projection: 256x192 tiles, grid 16x16 = 256 (1 block per CU)
  k_gemmQKV<<<256, 512, 0, stream>>>(xb, WqkvT, bqkv, ws, DM);

  // flash attention: split=4, grid 2048, KVBLK=64
  k_attn_split<<<2048, 256, 0, stream>>>(Qb, Kb, Vt, Opart, lpart);
  k_attn_merge<<<4096, 256, 0, stream>>>(Opart, lpart, Ob);

  // Wo projection: 256x128 tiles, split-K=2, bf16 partials at ATTN0/ATTN1
  k_gemmMN<<<256, 512, 0, stream>>>(Ob, WoT, bo, attn0, DM, DM / 2, DM,
                                    (OFF_ATTN1 - OFF_ATTN0) / 2, 8, 16);
  k_res_ln<false, true><<<4096, 256, 0, stream>>>(x, attn0, attn1, g1, b1,
                                                  nullptr, hb);

  // FFN1: 256^2 tiles, grid 16x16 = 256
  k_gemm256<EPI_GELU><<<256, 512, 0, stream>>>(hb, W1T, bf1, f1, DFF, DM, 16);

  // FFN2: 256x128 tiles, split-K=2, bf16 partials at FFN0/FFN1
  k_gemmMN<<<256, 512, 0, stream>>>(f1, W2T, bf2, ffn0, DM, DFF / 2, DFF,
                                    (OFF_FFN1 - OFF_FFN0) / 2, 8, 16);
  k_res_ln<true, false><<<4096, 256, 0, stream>>>(hb, ffn0, ffn1, g2, b2, out, nullptr);
}

// Round 18
// 231.957 us; speedup vs baseline: 1.1824x; 1.0179x over previous
//
#include <hip/hip_runtime.h>
#include <cstdint>
#include <cmath>

typedef unsigned short u16;
typedef unsigned int u32;
typedef unsigned long long u64;
typedef __bf16 bf16x8 __attribute__((ext_vector_type(8)));
typedef float f32x4 __attribute__((ext_vector_type(4)));
typedef float f32x16 __attribute__((ext_vector_type(16)));
typedef int v2i __attribute__((ext_vector_type(2)));

#define AS1 __attribute__((address_space(1)))
#define AS3 __attribute__((address_space(3)))

static constexpr int DM = 1024, DFF = 4096, SS = 2048, HH = 16, HD = 64, TT = 4096;
static constexpr size_t MiB = (size_t)1 << 20;
// workspace map (bytes) — live-range audited (r15):
static constexpr size_t OFF_WQKVT = 0;
static constexpr size_t OFF_WOT = 6 * MiB;
static constexpr size_t OFF_W1T = 8 * MiB;
static constexpr size_t OFF_W2T = 16 * MiB;
static constexpr size_t OFF_XB = 24 * MiB;
static constexpr size_t OFF_QB = 32 * MiB;
static constexpr size_t OFF_KB = 40 * MiB;
static constexpr size_t OFF_VT = 48 * MiB;
static constexpr size_t OFF_OPART = 56 * MiB;  // u16[2][65536][64] = 16 MiB
static constexpr size_t OFF_ML = 88 * MiB;
static constexpr size_t OFF_BQKV = 90 * MiB;
static constexpr size_t OFF_ATTN0 = 32 * MiB;  // bf16 partial, 8 MiB
static constexpr size_t OFF_ATTN1 = 40 * MiB;  // bf16 partial, 8 MiB
static constexpr size_t OFF_HB = 48 * MiB;     // bf16 h, 8 MiB
static constexpr size_t OFF_F1 = 56 * MiB;     // bf16 gelu out, 32 MiB
static constexpr size_t OFF_FFN0 = 24 * MiB;   // bf16 partial, 8 MiB
static constexpr size_t OFF_FFN1 = 32 * MiB;   // bf16 partial, 8 MiB

__device__ __forceinline__ u16 f2bf(float f) {
  union { float f; unsigned u; } c; c.f = f;
  unsigned r = c.u + 0x7fffu + ((c.u >> 16) & 1u);
  return (u16)(r >> 16);
}
__device__ __forceinline__ float bf2f(u16 h) {
  union { unsigned u; float f; } c; c.u = ((u32)h) << 16;
  return c.f;
}

__device__ __forceinline__ void gload_lds16(const void* g, void* l) {
  __builtin_amdgcn_global_load_lds((AS1 void*)g, (AS3 void*)l, 16, 0, 0);
}

__device__ __forceinline__ float exp2_(float x) {
#if __has_builtin(__builtin_amdgcn_exp2f)
  return __builtin_amdgcn_exp2f(x);
#else
  return exp2f(x);
#endif
}

__device__ __forceinline__ u32 cvt_pk_bf16(float lo, float hi) {
  u32 r;
  asm("v_cvt_pk_bf16_f32 %0, %1, %2" : "=v"(r) : "v"(lo), "v"(hi));
  return r;
}

__device__ __forceinline__ void lane32_swap(u32& a, u32& b) {
#if __has_builtin(__builtin_amdgcn_permlane32_swap)
  v2i r = __builtin_amdgcn_permlane32_swap((int)a, (int)b, false, false);
  a = (u32)r.x;
  b = (u32)r.y;
#else
  u32 ta = (u32)__shfl_xor((int)a, 32);
  u32 tb = (u32)__shfl_xor((int)b, 32);
  bool hi = (threadIdx.x & 32) != 0;
  u32 na = hi ? tb : a;
  u32 nb = hi ? b : ta;
  a = na;
  b = nb;
#endif
}

__device__ __forceinline__ float cross32_reduce_sum(float x) {
  u32 a = __float_as_uint(x), b = a;
  lane32_swap(a, b);
  return __uint_as_float(a) + __uint_as_float(b);
}

__device__ __forceinline__ int xcd_swizzle(int bid, int nwg) {
  int q8 = nwg >> 3;
  return (bid & 7) * q8 + (bid >> 3);
}

// ======== fused prep: cast x, transpose-cast 6 weights, concat biases ========
__global__ __launch_bounds__(256) void k_prep(const float* __restrict__ x,
                                              const float* __restrict__ Wq,
                                              const float* __restrict__ Wk,
                                              const float* __restrict__ Wv,
                                              const float* __restrict__ Wo,
                                              const float* __restrict__ W1,
                                              const float* __restrict__ W2,
                                              const float* __restrict__ bq,
                                              const float* __restrict__ bk,
                                              const float* __restrict__ bv,
                                              char* __restrict__ ws) {
  const int blk = blockIdx.x;
  const int tid = threadIdx.x;
  if (blk < 4096) {  // cast x -> xb
    u16* out = (u16*)(ws + OFF_XB);
    int i = blk * 256 + tid;
    float4 v = ((const float4*)x)[i];
    u64 pk = (u64)f2bf(v.x) | ((u64)f2bf(v.y) << 16) |
             ((u64)f2bf(v.z) << 32) | ((u64)f2bf(v.w) << 48);
    ((u64*)out)[i] = pk;
    return;
  }
  if (blk == 16384) {  // concat biases
    float* out = (float*)(ws + OFF_BQKV);
#pragma unroll
    for (int it = 0; it < 12; ++it) {
      int i = it * 256 + tid;
      out[i] = i < 1024 ? bq[i] : (i < 2048 ? bk[i - 1024] : bv[i - 2048]);
    }
    return;
  }
  const float* in;
  u16* out;
  int R, C, t;
  if (blk < 8192) {
    t = blk - 4096;
    const int w = t >> 10;
    t &= 1023;
    R = DM; C = DM;
    if (w == 0) { in = Wq; out = (u16*)(ws + OFF_WQKVT); }
    else if (w == 1) { in = Wk; out = (u16*)(ws + OFF_WQKVT) + 1024 * 1024; }
    else if (w == 2) { in = Wv; out = (u16*)(ws + OFF_WQKVT) + 2048 * 1024; }
    else { in = Wo; out = (u16*)(ws + OFF_WOT); }
  } else if (blk < 12288) {
    t = blk - 8192;
    R = DM; C = DFF;
    in = W1; out = (u16*)(ws + OFF_W1T);
  } else {
    t = blk - 12288;
    R = DFF; C = DM;
    in = W2; out = (u16*)(ws + OFF_W2T);
  }
  const int ntx = C >> 5;
  const int cb = (t % ntx) * 32, rb = (t / ntx) * 32;
  __shared__ u16 tile[32][33];
  const int tx = tid & 31;
  const int ty = tid >> 5;
#pragma unroll
  for (int i = 0; i < 4; i++) {
    int r = ty + i * 8;
    tile[r][tx] = f2bf(in[(size_t)(rb + r) * C + cb + tx]);
  }
  __syncthreads();
#pragma unroll
  for (int i = 0; i < 4; i++) {
    int r2 = ty + i * 8;
    out[(size_t)(cb + r2) * R + rb + tx] = tile[tx][r2];
  }
}

enum { EPI_F32 = 0, EPI_GELU = 1 };

// ======== 256x192 8-wave BK=64 QKV GEMM: grid 16x16=256 (1 block per CU) ========
__global__ __launch_bounds__(512) void k_gemmQKV(const u16* __restrict__ A,
                                                 const u16* __restrict__ Bt,
                                                 const float* __restrict__ bias,
                                                 char* __restrict__ wsb, int K) {
  __shared__ __align__(16) u16 smem[57344];  // 112 KiB
  const int tid = threadIdx.x;
  const int wid = tid >> 6, lane = tid & 63;
  const int lrow = lane & 15, lgrp = lane >> 4;
  const int wr = wid >> 2, wc = wid & 3;
  const int swz = xcd_swizzle(blockIdx.x, gridDim.x);
  const int mrow = (swz >> 4) * 256, ncol = (swz & 15) * 192;

  const int srow = tid >> 3;
  const int sgd = tid & 7;
  const int gsw = (sgd ^ (srow & 7)) << 3;
  const u16* aS0 = A + (size_t)(mrow + srow) * K + gsw;
  const u16* bS0 = Bt + (size_t)(ncol + srow) * K + gsw;
  const int T = K >> 6;

  auto stageA = [&](int t, int b) {
    u16* dst = smem + b * 28672 + wid * 512;
    const u16* s = aS0 + t * 64;
#pragma unroll
    for (int c = 0; c < 4; ++c) gload_lds16(s + (size_t)c * 64 * K, dst + c * 4096);
  };
  auto stageB = [&](int t, int b) {
    u16* dst = smem + b * 28672 + 16384 + wid * 512;
    const u16* s = bS0 + t * 64;
#pragma unroll
    for (int c = 0; c < 3; ++c) gload_lds16(s + (size_t)c * 64 * K, dst + c * 4096);
  };

  f32x4 acc[8][3];
#pragma unroll
  for (int m = 0; m < 8; ++m)
#pragma unroll
    for (int n = 0; n < 3; ++n) acc[m][n] = (f32x4){0.f, 0.f, 0.f, 0.f};

  stageA(0, 0);
  stageB(0, 0);
  asm volatile("s_waitcnt vmcnt(0)" ::: "memory");
  __builtin_amdgcn_s_barrier();

  const int arow_base = wr * 128 + lrow;
  const int brow_base = wc * 48 + lrow;
  const int aswz = lrow & 7;

  for (int t = 0; t < T; ++t) {
    const u16* Abuf = smem + (t & 1) * 28672;
    const u16* Bbuf = smem + (t & 1) * 28672 + 16384;
    bf16x8 af[4][2], bfr[3][2];
#pragma unroll
    for (int m = 0; m < 4; ++m)
#pragma unroll
      for (int ks = 0; ks < 2; ++ks)
        af[m][ks] = *(const bf16x8*)(Abuf + (arow_base + m * 16) * 64 +
                                     (((ks * 4 + lgrp) ^ aswz) << 3));
#pragma unroll
    for (int n = 0; n < 3; ++n)
#pragma unroll
      for (int ks = 0; ks < 2; ++ks)
        bfr[n][ks] = *(const bf16x8*)(Bbuf + (brow_base + n * 16) * 64 +
                                      (((ks * 4 + lgrp) ^ aswz) << 3));
    if (t + 1 < T) stageA(t + 1, (t + 1) & 1);
    __builtin_amdgcn_s_barrier();
    __builtin_amdgcn_s_setprio(1);
#pragma unroll
    for (int m = 0; m < 4; ++m)
#pragma unroll
      for (int n = 0; n < 2; ++n)
#pragma unroll
        for (int ks = 0; ks < 2; ++ks)
          acc[m][n] = __builtin_amdgcn_mfma_f32_16x16x32_bf16(af[m][ks], bfr[n][ks],
                                                              acc[m][n], 0, 0, 0);
    __builtin_amdgcn_s_setprio(0);
    if (t + 1 < T) stageB(t + 1, (t + 1) & 1);
    __builtin_amdgcn_s_barrier();
    __builtin_amdgcn_s_setprio(1);
#pragma unroll
    for (int m = 0; m < 4; ++m)
#pragma unroll
      for (int ks = 0; ks < 2; ++ks)
        acc[m][2] = __builtin_amdgcn_mfma_f32_16x16x32_bf16(af[m][ks], bfr[2][ks],
                                                            acc[m][2], 0, 0, 0);
    __builtin_amdgcn_s_setprio(0);
#pragma unroll
    for (int m = 0; m < 4; ++m)
#pragma unroll
      for (int ks = 0; ks < 2; ++ks)
        af[m][ks] = *(const bf16x8*)(Abuf + (arow_base + (m + 4) * 16) * 64 +
                                     (((ks * 4 + lgrp) ^ aswz) << 3));
    __builtin_amdgcn_s_barrier();
    __builtin_amdgcn_s_setprio(1);
#pragma unroll
    for (int m = 0; m < 4; ++m)
#pragma unroll
      for (int n = 0; n < 2; ++n)
#pragma unroll
        for (int ks = 0; ks < 2; ++ks)
          acc[m + 4][n] = __builtin_amdgcn_mfma_f32_16x16x32_bf16(af[m][ks], bfr[n][ks],
                                                                  acc[m + 4][n], 0, 0, 0);
    __builtin_amdgcn_s_setprio(0);
    __builtin_amdgcn_s_barrier();
    __builtin_amdgcn_s_setprio(1);
#pragma unroll
    for (int m = 0; m < 4; ++m)
#pragma unroll
      for (int ks = 0; ks < 2; ++ks)
        acc[m + 4][2] = __builtin_amdgcn_mfma_f32_16x16x32_bf16(af[m][ks], bfr[2][ks],
                                                                acc[m + 4][2], 0, 0, 0);
    __builtin_amdgcn_s_setprio(0);
    if (t + 1 < T) {
      asm volatile("s_waitcnt vmcnt(0)" ::: "memory");
      __builtin_amdgcn_s_barrier();
      __builtin_amdgcn_sched_barrier(0);
    }
  }

#pragma unroll
  for (int m = 0; m < 8; ++m) {
#pragma unroll
    for (int n = 0; n < 3; ++n) {
      const int row0 = mrow + wr * 128 + m * 16 + lgrp * 4;
      const int col = ncol + wc * 48 + n * 16 + lrow;
      const float bv = bias[col];
      f32x4 v = acc[m][n];
      const int seg = col >> 10, cc = col & 1023;
      const int h = cc >> 6, d = cc & 63;
      if (seg < 2) {
        u16* dst = (u16*)(wsb + (seg == 0 ? OFF_QB : OFF_KB));
#pragma unroll
        for (int r = 0; r < 4; r++) {
          const int row = row0 + r;
          const int b = row >> 11, s = row & 2047;
          dst[((size_t)(b * HH + h) * SS + s) * HD + d] = f2bf(v[r] + bv);
        }
      } else {
        u16* Vt = (u16*)(wsb + OFF_VT);
        const int b = row0 >> 11, s = row0 & 2047;
        u64 pk = (u64)f2bf(v[0] + bv) | ((u64)f2bf(v[1] + bv) << 16) |
                 ((u64)f2bf(v[2] + bv) << 32) | ((u64)f2bf(v[3] + bv) << 48);
        size_t addr = ((size_t)(b * HH + h) * (SS / 64) + (s >> 6)) * 4096 +
                      (size_t)d * 64 + (s & 63);
        *(u64*)&Vt[addr] = pk;
      }
    }
  }
}

// ======== 256x256 8-wave BK=64 deep-pipelined GEMM (full K), XCD-swizzled ========
template <int EPI>
__global__ __launch_bounds__(512) void k_gemm256(const u16* __restrict__ A,
                                                 const u16* __restrict__ Bt,
                                                 const float* __restrict__ bias,
                                                 void* __restrict__ Cout,
                                                 int N, int K, int nx) {
  __shared__ __align__(16) u16 smem[65536];  // 128 KiB
  const int tid = threadIdx.x;
  const int wid = tid >> 6, lane = tid & 63;
  const int lrow = lane & 15, lgrp = lane >> 4;
  const int wr = wid >> 2, wc = wid & 3;
  const int swz = xcd_swizzle(blockIdx.x, gridDim.x);
  const int mrow = (swz / nx) * 256, ncol = (swz % nx) * 256;

  const int srow = tid >> 3;
  const int sgd = tid & 7;
  const int gsw = (sgd ^ (srow & 7)) << 3;
  const u16* aS0 = A + (size_t)(mrow + srow) * K + gsw;
  const u16* bS0 = Bt + (size_t)(ncol + srow) * K + gsw;
  const int T = K >> 6;

  auto stageA = [&](int t, int b) {
    u16* dst = smem + b * 32768 + wid * 512;
    const u16* s = aS0 + t * 64;
#pragma unroll
    for (int c = 0; c < 4; ++c) gload_lds16(s + (size_t)c * 64 * K, dst + c * 4096);
  };
  auto stageB = [&](int t, int b) {
    u16* dst = smem + b * 32768 + 16384 + wid * 512;
    const u16* s = bS0 + t * 64;
#pragma unroll
    for (int c = 0; c < 4; ++c) gload_lds16(s + (size_t)c * 64 * K, dst + c * 4096);
  };

  f32x4 acc[8][4];
#pragma unroll
  for (int m = 0; m < 8; ++m)
#pragma unroll
    for (int n = 0; n < 4; ++n) acc[m][n] = (f32x4){0.f, 0.f, 0.f, 0.f};

  stageA(0, 0);
  stageB(0, 0);
  asm volatile("s_waitcnt vmcnt(0)" ::: "memory");
  __builtin_amdgcn_s_barrier();

  const int arow_base = wr * 128 + lrow;
  const int brow_base = wc * 64 + lrow;
  const int aswz = lrow & 7;

  for (int t = 0; t < T; ++t) {
    const int cb = (t & 1) * 32768;
    const u16* Abuf = smem + cb;
    const u16* Bbuf = smem + cb + 16384;
    bf16x8 af[4][2], bfr[4][2];
#pragma unroll
    for (int m = 0; m < 4; ++m)
#pragma unroll
      for (int ks = 0; ks < 2; ++ks)
        af[m][ks] = *(const bf16x8*)(Abuf + (arow_base + m * 16) * 64 +
                                     (((ks * 4 + lgrp) ^ aswz) << 3));
#pragma unroll
    for (int n = 0; n < 4; ++n)
#pragma unroll
      for (int ks = 0; ks < 2; ++ks)
        bfr[n][ks] = *(const bf16x8*)(Bbuf + (brow_base + n * 16) * 64 +
                                      (((ks * 4 + lgrp) ^ aswz) << 3));
    if (t + 1 < T) stageA(t + 1, (t + 1) & 1);
    __builtin_amdgcn_s_barrier();
    __builtin_amdgcn_s_setprio(1);
#pragma unroll
    for (int m = 0; m < 4; ++m)
#pragma unroll
      for (int n = 0; n < 2; ++n)
#pragma unroll
        for (int ks = 0; ks < 2; ++ks)
          acc[m][n] = __builtin_amdgcn_mfma_f32_16x16x32_bf16(af[m][ks], bfr[n][ks],
                                                              acc[m][n], 0, 0, 0);
    __builtin_amdgcn_s_setprio(0);
    if (t + 1 < T) stageB(t + 1, (t + 1) & 1);
    __builtin_amdgcn_s_barrier();
    __builtin_amdgcn_s_setprio(1);
#pragma unroll
    for (int m = 0; m < 4; ++m)
#pragma unroll
      for (int n = 2; n < 4; ++n)
#pragma unroll
        for (int ks = 0; ks < 2; ++ks)
          acc[m][n] = __builtin_amdgcn_mfma_f32_16x16x32_bf16(af[m][ks], bfr[n][ks],
                                                              acc[m][n], 0, 0, 0);
    __builtin_amdgcn_s_setprio(0);
#pragma unroll
    for (int m = 0; m < 4; ++m)
#pragma unroll
      for (int ks = 0; ks < 2; ++ks)
        af[m][ks] = *(const bf16x8*)(Abuf + (arow_base + (m + 4) * 16) * 64 +
                                     (((ks * 4 + lgrp) ^ aswz) << 3));
    __builtin_amdgcn_s_barrier();
    __builtin_amdgcn_s_setprio(1);
#pragma unroll
    for (int m = 0; m < 4; ++m)
#pragma unroll
      for (int n = 0; n < 2; ++n)
#pragma unroll
        for (int ks = 0; ks < 2; ++ks)
          acc[m + 4][n] = __builtin_amdgcn_mfma_f32_16x16x32_bf16(af[m][ks], bfr[n][ks],
                                                                  acc[m + 4][n], 0, 0, 0);
    __builtin_amdgcn_s_setprio(0);
    __builtin_amdgcn_s_barrier();
    __builtin_amdgcn_s_setprio(1);
#pragma unroll
    for (int m = 0; m < 4; ++m)
#pragma unroll
      for (int n = 2; n < 4; ++n)
#pragma unroll
        for (int ks = 0; ks < 2; ++ks)
          acc[m + 4][n] = __builtin_amdgcn_mfma_f32_16x16x32_bf16(af[m][ks], bfr[n][ks],
                                                                  acc[m + 4][n], 0, 0, 0);
    __builtin_amdgcn_s_setprio(0);
    if (t + 1 < T) {
      asm volatile("s_waitcnt vmcnt(0)" ::: "memory");
      __builtin_amdgcn_s_barrier();
      __builtin_amdgcn_sched_barrier(0);
    }
  }

#pragma unroll
  for (int m = 0; m < 8; ++m) {
#pragma unroll
    for (int n = 0; n < 4; ++n) {
      const int row0 = mrow + wr * 128 + m * 16 + lgrp * 4;
      const int col = ncol + wc * 64 + n * 16 + lrow;
      f32x4 v = acc[m][n];
      if constexpr (EPI == EPI_GELU) {
        const float bv = bias[col];
        u16* C = (u16*)Cout;
#pragma unroll
        for (int r = 0; r < 4; r++) {
          float xg = v[r] + bv;
          float gl = 0.5f * xg * (1.0f + erff(xg * 0.70710678118654752f));
          C[(size_t)(row0 + r) * N + col] = f2bf(gl);
        }
      } else {
        const float bv = bias[col];
        float* C = (float*)Cout;
#pragma unroll
        for (int r = 0; r < 4; r++) C[(size_t)(row0 + r) * N + col] = v[r] + bv;
      }
    }
  }
}

// ======== 256x128 8-wave BK=64 GEMM, split-K, bf16 partial output ========
__global__ __launch_bounds__(512) void k_gemmMN(const u16* __restrict__ A,
                                                const u16* __restrict__ Bt,
                                                const float* __restrict__ bias,
                                                u16* __restrict__ Cout,
                                                int N, int Ksub, int stride,
                                                size_t zoff, int nx, int ny) {
  __shared__ __align__(16) u16 smem[49152];  // 96 KiB
  const int tid = threadIdx.x;
  const int wid = tid >> 6, lane = tid & 63;
  const int lrow = lane & 15, lgrp = lane >> 4;
  const int wr = wid >> 2, wc = wid & 3;
  const int swz = xcd_swizzle(blockIdx.x, gridDim.x);
  const int bx = swz % nx;
  const int by = (swz / nx) % ny;
  const int bz = swz / (nx * ny);
  const int mrow = by * 256, ncol = bx * 128;

  const int srow = tid >> 3;
  const int sgd = tid & 7;
  const int gsw = (sgd ^ (srow & 7)) << 3;
  const u16* aS0 = A + (size_t)(mrow + srow) * stride + (size_t)bz * Ksub + gsw;
  const u16* bS0 = Bt + (size_t)(ncol + srow) * stride + (size_t)bz * Ksub + gsw;
  const int T = Ksub >> 6;

  auto stageA = [&](int t, int b) {
    u16* dst = smem + b * 24576 + wid * 512;
    const u16* s = aS0 + t * 64;
#pragma unroll
    for (int c = 0; c < 4; ++c) gload_lds16(s + (size_t)c * 64 * stride, dst + c * 4096);
  };
  auto stageB = [&](int t, int b) {
    u16* dst = smem + b * 24576 + 16384 + wid * 512;
    const u16* s = bS0 + t * 64;
#pragma unroll
    for (int c = 0; c < 2; ++c) gload_lds16(s + (size_t)c * 64 * stride, dst + c * 4096);
  };

  f32x4 acc[8][2];
#pragma unroll
  for (int m = 0; m < 8; ++m)
#pragma unroll
    for (int n = 0; n < 2; ++n) acc[m][n] = (f32x4){0.f, 0.f, 0.f, 0.f};

  stageA(0, 0);
  stageB(0, 0);
  asm volatile("s_waitcnt vmcnt(0)" ::: "memory");
  __builtin_amdgcn_s_barrier();

  const int arow_base = wr * 128 + lrow;
  const int brow_base = wc * 32 + lrow;
  const int aswz = lrow & 7;

  for (int t = 0; t < T; ++t) {
    const int cb = (t & 1) * 24576;
    const u16* Abuf = smem + cb;
    const u16* Bbuf = smem + cb + 16384;
    bf16x8 af[4][2], bfr[2][2];
#pragma unroll
    for (int m = 0; m < 4; ++m)
#pragma unroll
      for (int ks = 0; ks < 2; ++ks)
        af[m][ks] = *(const bf16x8*)(Abuf + (arow_base + m * 16) * 64 +
                                     (((ks * 4 + lgrp) ^ aswz) << 3));
#pragma unroll
    for (int n = 0; n < 2; ++n)
#pragma unroll
      for (int ks = 0; ks < 2; ++ks)
        bfr[n][ks] = *(const bf16x8*)(Bbuf + (brow_base + n * 16) * 64 +
                                      (((ks * 4 + lgrp) ^ aswz) << 3));
    if (t + 1 < T) stageA(t + 1, (t + 1) & 1);
    __builtin_amdgcn_s_barrier();
    __builtin_amdgcn_s_setprio(1);
#pragma unroll
    for (int m = 0; m < 4; ++m)
#pragma unroll
      for (int ks = 0; ks < 2; ++ks)
        acc[m][0] = __builtin_amdgcn_mfma_f32_16x16x32_bf16(af[m][ks], bfr[0][ks],
                                                            acc[m][0], 0, 0, 0);
    __builtin_amdgcn_s_setprio(0);
    if (t + 1 < T) stageB(t + 1, (t + 1) & 1);
    __builtin_amdgcn_s_barrier();
    __builtin_amdgcn_s_setprio(1);
#pragma unroll
    for (int m = 0; m < 4; ++m)
#pragma unroll
      for (int ks = 0; ks < 2; ++ks)
        acc[m][1] = __builtin_amdgcn_mfma_f32_16x16x32_bf16(af[m][ks], bfr[1][ks],
                                                            acc[m][1], 0, 0, 0);
    __builtin_amdgcn_s_setprio(0);
#pragma unroll
    for (int m = 0; m < 4; ++m)
#pragma unroll
      for (int ks = 0; ks < 2; ++ks)
        af[m][ks] = *(const bf16x8*)(Abuf + (arow_base + (m + 4) * 16) * 64 +
                                     (((ks * 4 + lgrp) ^ aswz) << 3));
    __builtin_amdgcn_s_barrier();
    __builtin_amdgcn_s_setprio(1);
#pragma unroll
    for (int m = 0; m < 4; ++m)
#pragma unroll
      for (int ks = 0; ks < 2; ++ks)
        acc[m + 4][0] = __builtin_amdgcn_mfma_f32_16x16x32_bf16(af[m][ks], bfr[0][ks],
                                                                acc[m + 4][0], 0, 0, 0);
    __builtin_amdgcn_s_setprio(0);
    __builtin_amdgcn_s_barrier();
    __builtin_amdgcn_s_setprio(1);
#pragma unroll
    for (int m = 0; m < 4; ++m)
#pragma unroll
      for (int ks = 0; ks < 2; ++ks)
        acc[m + 4][1] = __builtin_amdgcn_mfma_f32_16x16x32_bf16(af[m][ks], bfr[1][ks],
                                                                acc[m + 4][1], 0, 0, 0);
    __builtin_amdgcn_s_setprio(0);
    if (t + 1 < T) {
      asm volatile("s_waitcnt vmcnt(0)" ::: "memory");
      __builtin_amdgcn_s_barrier();
      __builtin_amdgcn_sched_barrier(0);
    }
  }

  u16* C = Cout + (size_t)bz * zoff;
#pragma unroll
  for (int m = 0; m < 8; ++m) {
#pragma unroll
    for (int n = 0; n < 2; ++n) {
      const int row0 = mrow + wr * 128 + m * 16 + lgrp * 4;
      const int col = ncol + wc * 32 + n * 16 + lrow;
      const float bv = (bz == 0) ? bias[col] : 0.0f;
      f32x4 v = acc[m][n];
#pragma unroll
      for (int r = 0; r < 4; r++) C[(size_t)(row0 + r) * N + col] = f2bf(v[r] + bv);
    }
  }
}

// ---------------- flash attention, KV-split=2, KVBLK=64, fixed-C softmax ----------------
__global__ __launch_bounds__(256) void k_attn_split(const u16* __restrict__ Q,
                                                    const u16* __restrict__ K,
                                                    const u16* __restrict__ Vt,
                                                    u16* __restrict__ Opart,
                                                    float* __restrict__ lpart) {
  __shared__ __align__(16) u16 Kl[2][4096];
  __shared__ __align__(16) u16 Vl[2][4096];
  const int tid = threadIdx.x, wid = tid >> 6, lane = tid & 63;
  const int ql = lane & 31, hi = lane >> 5;
  const int bx = blockIdx.x;
  const int split = bx >> 9, bh = (bx >> 4) & 31, qblk = bx & 15;
  const int qbase = qblk * 128 + wid * 32;
  const int kvS = split * 1024;
  const u16* Qh = Q + (size_t)bh * SS * HD;
  const u16* Kh = K + (size_t)bh * SS * HD;
  const u16* Vh = Vt + (size_t)bh * SS * HD;

  const int lrow3 = lane >> 3;
  const int lin = lrow3 * 128 + ((((lane & 7) << 4)) ^ (lrow3 << 4));
  const int kswz = (ql & 7) << 4;

  auto stage = [&](int kv0, int bufi) {
    const char* Ks = (const char*)Kh + (size_t)kv0 * 128 + wid * 2048 + lin;
    const char* Vs = (const char*)Vh + ((size_t)(kv0 >> 6)) * 8192 + wid * 2048 + lin;
    char* kd = (char*)&Kl[bufi][0] + wid * 2048;
    char* vd = (char*)&Vl[bufi][0] + wid * 2048;
    gload_lds16(Ks, kd);
    gload_lds16(Ks + 1024, kd + 1024);
    gload_lds16(Vs, vd);
    gload_lds16(Vs + 1024, vd + 1024);
  };

  bf16x8 qf[4];
#pragma unroll
  for (int j = 0; j < 4; j++)
    qf[j] = *(const bf16x8*)&Qh[(size_t)(qbase + ql) * HD + j * 16 + hi * 8];

  f32x16 oacc0, oacc1;
#pragma unroll
  for (int r = 0; r < 16; r++) { oacc0[r] = 0.f; oacc1[r] = 0.f; }
  float lsum = 0.f;
  const float cs = 0.125f * 1.44269504f;
  const float CSHIFT = 24.0f;

  auto tileC = [&](int bufi, int tt) {
    const char* Kb = (const char*)&Kl[bufi][0];
    const char* Vb = (const char*)&Vl[bufi][0];
    bf16x8 kf[4];
#pragma unroll
    for (int j = 0; j < 4; j++)
      kf[j] = *(const bf16x8*)(Kb + (tt * 32 + ql) * 128 + ((j * 32 + hi * 16) ^ kswz));

    f32x16 s;
#pragma unroll
    for (int r = 0; r < 16; r++) s[r] = 0.f;
#pragma unroll
    for (int j = 0; j < 4; j++)
      s = __builtin_amdgcn_mfma_f32_32x32x16_bf16(kf[j], qf[j], s, 0, 0, 0);

    float p[16];
#pragma unroll
    for (int r = 0; r < 16; r++) p[r] = exp2_(fmaf(s[r], cs, -CSHIFT));
    float t0 = (p[0] + p[1]) + (p[2] + p[3]);
    float t1 = (p[4] + p[5]) + (p[6] + p[7]);
    float t2 = (p[8] + p[9]) + (p[10] + p[11]);
    float t3 = (p[12] + p[13]) + (p[14] + p[15]);
    lsum += cross32_reduce_sum((t0 + t1) + (t2 + t3));

    u32 w01 = cvt_pk_bf16(p[0], p[1]), w23 = cvt_pk_bf16(p[2], p[3]);
    u32 w45 = cvt_pk_bf16(p[4], p[5]), w67 = cvt_pk_bf16(p[6], p[7]);
    u32 w89 = cvt_pk_bf16(p[8], p[9]), wab = cvt_pk_bf16(p[10], p[11]);
    u32 wcd = cvt_pk_bf16(p[12], p[13]), wef = cvt_pk_bf16(p[14], p[15]);
    lane32_swap(w01, w45);
    lane32_swap(w23, w67);
    lane32_swap(w89, wcd);
    lane32_swap(wab, wef);
    union { u32 w[4]; bf16x8 v; } f0, f1;
    f0.w[0] = w01; f0.w[1] = w23; f0.w[2] = w45; f0.w[3] = w67;
    f1.w[0] = w89; f1.w[1] = wab; f1.w[2] = wcd; f1.w[3] = wef;

    bf16x8 vf[4];
#pragma unroll
    for (int u = 0; u < 4; u++)
      vf[u] = *(const bf16x8*)(Vb + ((u >> 1) * 32 + ql) * 128 +
                               ((tt * 64 + (u & 1) * 32 + hi * 16) ^ kswz));

    oacc0 = __builtin_amdgcn_mfma_f32_32x32x16_bf16(vf[0], f0.v, oacc0, 0, 0, 0);
    oacc0 = __builtin_amdgcn_mfma_f32_32x32x16_bf16(vf[1], f1.v, oacc0, 0, 0, 0);
    oacc1 = __builtin_amdgcn_mfma_f32_32x32x16_bf16(vf[2], f0.v, oacc1, 0, 0, 0);
    oacc1 = __builtin_amdgcn_mfma_f32_32x32x16_bf16(vf[3], f1.v, oacc1, 0, 0, 0);
  };

  stage(kvS, 0);
  __syncthreads();
  int cur = 0;
  for (int it = 0; it < 16; ++it) {
    if (it + 1 < 16) stage(kvS + (it + 1) * 64, cur ^ 1);
    tileC(cur, 0);
    tileC(cur, 1);
    __syncthreads();
    cur ^= 1;
  }

  const int rowidx = bh * SS + qbase + ql;
  u16* Orow = Opart + ((size_t)split * 32 * SS + rowidx) * HD;
  auto storeAcc = [&](const f32x16& a, int dbase) {
#pragma unroll
    for (int t = 0; t < 4; t++) {
      u64 pk = (u64)f2bf(a[4 * t]) | ((u64)f2bf(a[4 * t + 1]) << 16) |
               ((u64)f2bf(a[4 * t + 2]) << 32) | ((u64)f2bf(a[4 * t + 3]) << 48);
      *(u64*)&Orow[dbase + 4 * hi + 8 * t] = pk;
    }
  };
  storeAcc(oacc0, 0);
  storeAcc(oacc1, 32);
  if (hi == 0) lpart[(size_t)split * 32 * SS + rowidx] = lsum;
}

// ---------------- merge the 2 KV-split partials (plain sums) -> bf16 O ----------------
__global__ __launch_bounds__(256) void k_attn_merge(const u16* __restrict__ Opart,
                                                    const float* __restrict__ lpart,
                                                    u16* __restrict__ O) {
  const int g = blockIdx.x * 256 + threadIdx.x;
  const int row = g >> 4, dseg = g & 15;
  float denom = lpart[row] + lpart[(size_t)32 * SS + row];
  const float inv = 1.0f / denom;
  float acc[4] = {0.f, 0.f, 0.f, 0.f};
#pragma unroll
  for (int s = 0; s < 2; s++) {
    u64 pk = *(const u64*)&Opart[(((size_t)s * 32 * SS + row) * HD) + dseg * 4];
#pragma unroll
    for (int k = 0; k < 4; k++) acc[k] += bf2f((u16)(pk >> (16 * k)));
  }
  const int bh = row >> 11, s2 = row & 2047;
  const int bb = bh >> 4, h = bh & 15;
  u64 pk = (u64)f2bf(acc[0] * inv) | ((u64)f2bf(acc[1] * inv) << 16) |
           ((u64)f2bf(acc[2] * inv) << 32) | ((u64)f2bf(acc[3] * inv) << 48);
  *(u64*)&O[((size_t)(bb * SS + s2) * DM) + h * HD + dseg * 4] = pk;
}

// ---------------- fused residual(2-way) + layernorm ----------------
template <bool XBF, bool WB>
__global__ __launch_bounds__(256) void k_res_ln(const void* __restrict__ Xv,
                                                const u16* __restrict__ Y0,
                                                const u16* __restrict__ Y1,
                                                const float* __restrict__ gw,
                                                const float* __restrict__ bw,
                                                float* __restrict__ outf,
                                                u16* __restrict__ outb) {
  const int row = blockIdx.x, t = threadIdx.x;
  float x0, x1, x2, x3;
  if constexpr (XBF) {
    u64 pk = ((const u64*)Xv)[(size_t)row * 256 + t];
    x0 = bf2f((u16)pk);
    x1 = bf2f((u16)(pk >> 16));
    x2 = bf2f((u16)(pk >> 32));
    x3 = bf2f((u16)(pk >> 48));
  } else {
    float4 xv = ((const float4*)Xv)[(size_t)row * 256 + t];
    x0 = xv.x; x1 = xv.y; x2 = xv.z; x3 = xv.w;
  }
  const u64 p0 = ((const u64*)Y0)[(size_t)row * 256 + t];
  const u64 p1 = ((const u64*)Y1)[(size_t)row * 256 + t];
  float v0 = x0 + bf2f((u16)p0) + bf2f((u16)p1);
  float v1 = x1 + bf2f((u16)(p0 >> 16)) + bf2f((u16)(p1 >> 16));
  float v2 = x2 + bf2f((u16)(p0 >> 32)) + bf2f((u16)(p1 >> 32));
  float v3 = x3 + bf2f((u16)(p0 >> 48)) + bf2f((u16)(p1 >> 48));
  float s = v0 + v1 + v2 + v3;
  float s2 = v0 * v0 + v1 * v1 + v2 * v2 + v3 * v3;
#pragma unroll
  for (int off = 32; off >= 1; off >>= 1) {
    s += __shfl_down(s, off);
    s2 += __shfl_down(s2, off);
  }
  __shared__ float ps[4], ps2[4];
  const int wid = t >> 6, lane = t & 63;
  if (lane == 0) { ps[wid] = s; ps2[wid] = s2; }
  __syncthreads();
  const float ts = ps[0] + ps[1] + ps[2] + ps[3];
  const float ts2 = ps2[0] + ps2[1] + ps2[2] + ps2[3];
  const float mu = ts * (1.f / 1024.f);
  const float rs = rsqrtf(ts2 * (1.f / 1024.f) - mu * mu + 1e-5f);
  const float4 g4 = ((const float4*)gw)[t];
  const float4 b4 = ((const float4*)bw)[t];
  float o0 = (v0 - mu) * rs * g4.x + b4.x;
  float o1 = (v1 - mu) * rs * g4.y + b4.y;
  float o2 = (v2 - mu) * rs * g4.z + b4.z;
  float o3 = (v3 - mu) * rs * g4.w + b4.w;
  if constexpr (WB) {
    u64 pk = (u64)f2bf(o0) | ((u64)f2bf(o1) << 16) | ((u64)f2bf(o2) << 32) |
             ((u64)f2bf(o3) << 48);
    ((u64*)(outb + (size_t)row * DM))[t] = pk;
  } else {
    ((float4*)(outf + (size_t)row * DM))[t] = make_float4(o0, o1, o2, o3);
  }
}

extern "C" void kernel_launch(void* const* d_in, const int* in_sizes, int n_in,
                              void* d_out, int out_size, void* d_ws, size_t ws_size,
                              hipStream_t stream) {
  const float* x = (const float*)d_in[0];
  const float* Wq = (const float*)d_in[1];
  const float* bq = (const float*)d_in[2];
  const float* Wk = (const float*)d_in[3];
  const float* bk = (const float*)d_in[4];
  const float* Wv = (const float*)d_in[5];
  const float* bv = (const float*)d_in[6];
  const float* Wo = (const float*)d_in[7];
  const float* bo = (const float*)d_in[8];
  const float* g1 = (const float*)d_in[9];
  const float* b1 = (const float*)d_in[10];
  const float* g2 = (const float*)d_in[11];
  const float* b2 = (const float*)d_in[12];
  const float* W1 = (const float*)d_in[13];
  const float* bf1 = (const float*)d_in[14];
  const float* W2 = (const float*)d_in[15];
  const float* bf2 = (const float*)d_in[16];
  float* out = (float*)d_out;

  if (ws_size < 92 * MiB) return;
  char* ws = (char*)d_ws;
  u16* WqkvT = (u16*)(ws + OFF_WQKVT);
  u16* WoT = (u16*)(ws + OFF_WOT);
  u16* W1T = (u16*)(ws + OFF_W1T);
  u16* W2T = (u16*)(ws + OFF_W2T);
  u16* xb = (u16*)(ws + OFF_XB);
  u16* Qb = (u16*)(ws + OFF_QB);
  u16* Kb = (u16*)(ws + OFF_KB);
  u16* Vt = (u16*)(ws + OFF_VT);
  u16* Ob = (u16*)(ws + OFF_XB);
  u16* Opart = (u16*)(ws + OFF_OPART);
  float* lpart = (float*)(ws + OFF_ML);
  float* bqkv = (float*)(ws + OFF_BQKV);
  u16* attn0 = (u16*)(ws + OFF_ATTN0);
  u16* attn1 = (u16*)(ws + OFF_ATTN1);
  u16* hb = (u16*)(ws + OFF_HB);
  u16* f1 = (u16*)(ws + OFF_F1);
  u16* ffn0 = (u16*)(ws + OFF_FFN0);
  u16* ffn1 = (u16*)(ws + OFF_FFN1);

  // fused prep: cast + 6 transposes + bias concat in one launch
  k_prep<<<16385, 256, 0, stream>>>(x, Wq, Wk, Wv, Wo, W1, W2, bq, bk, bv, ws);

  // fused QKV projection: 256x192 tiles, grid 16x16 = 256 (1 block per CU)
  k_gemmQKV<<<256, 512, 0, stream>>>(xb, WqkvT, bqkv, ws, DM);

  // flash attention: split=2, grid 1024, KVBLK=64
  k_attn_split<<<1024, 256, 0, stream>>>(Qb, Kb, Vt, Opart, lpart);
  k_attn_merge<<<4096, 256, 0, stream>>>(Opart, lpart, Ob);

  // Wo projection: 256x128 tiles, split-K=2, bf16 partials at ATTN0/ATTN1
  k_gemmMN<<<256, 512, 0, stream>>>(Ob, WoT, bo, attn0, DM, DM / 2, DM,
                                    (OFF_ATTN1 - OFF_ATTN0) / 2, 8, 16);
  k_res_ln<false, true><<<4096, 256, 0, stream>>>(x, attn0, attn1, g1, b1,
                                                  nullptr, hb);

  // FFN1: 256^2 tiles, grid 16x16 = 256
  k_gemm256<EPI_GELU><<<256, 512, 0, stream>>>(hb, W1T, bf1, f1, DFF, DM, 16);

  // FFN2: 256x128 tiles, split-K=2, bf16 partials at FFN0/FFN1
  k_gemmMN<<<256, 512, 0, stream>>>(f1, W2T, bf2, ffn0, DM, DFF / 2, DFF,
                                    (OFF_FFN1 - OFF_FFN0) / 2, 8, 16);
  k_res_ln<true, false><<<4096, 256, 0, stream>>>(hb, ffn0, ffn1, g2, b2, out, nullptr);
}